// Round 2
// baseline (1409.685 us; speedup 1.0000x reference)
//
#include <hip/hip_runtime.h>
#include <hip/hip_bf16.h>
#include <math.h>

#define BATCH 4096
#define HID 256
#define NG 1024   // 4*HID
#define OBS_D 400
#define OUT_W 15

__device__ __forceinline__ float sigf(float x) { return 1.0f / (1.0f + __expf(-x)); }
__device__ __forceinline__ float tanh_fast(float x) { return 1.0f - 2.0f / (__expf(2.0f * x) + 1.0f); }

// ---------------------------------------------------------------------------
// Prep: weight transposes + per-step fused biases + samp gather tables
// ---------------------------------------------------------------------------
__global__ __launch_bounds__(256) void prep_kernel(
    const float* __restrict__ W_ih, const float* __restrict__ W_hh,
    const float* __restrict__ b_ih, const float* __restrict__ b_hh,
    const float* __restrict__ addr_emb, const float* __restrict__ pid_emb,
    const float* __restrict__ sid_emb,
    const float* __restrict__ mlp_w2, const float* __restrict__ mlp_w3,
    float* __restrict__ W_ih_T, float* __restrict__ W_hh_T,
    float* __restrict__ bias_all, float* __restrict__ pid_rows,
    float* __restrict__ sid_rows, float* __restrict__ w2t, float* __restrict__ w3t)
{
    int blk = blockIdx.x, t = threadIdx.x;
    if (blk < 112) {
        // W_ih (1024x432) -> W_ih_T (432x1024), 64x64 tiles (16 j-tiles x 7 k-tiles)
        __shared__ float tile[64][65];
        int j0 = (blk & 15) * 64;
        int k0 = (blk >> 4) * 64;
        for (int i = t; i < 4096; i += 256) {
            int r = i >> 6, c = i & 63;
            int k = k0 + c;
            tile[r][c] = (k < 432) ? W_ih[(size_t)(j0 + r) * 432 + k] : 0.f;
        }
        __syncthreads();
        for (int i = t; i < 4096; i += 256) {
            int r = i >> 6, c = i & 63;
            int k = k0 + r;
            if (k < 432) W_ih_T[(size_t)k * 1024 + j0 + c] = tile[c][r];
        }
    } else if (blk < 176) {
        // W_hh (1024x256) -> W_hh_T (256x1024)
        __shared__ float tile[64][65];
        int bb = blk - 112;
        int j0 = (bb & 15) * 64;
        int k0 = (bb >> 4) * 64;  // 4 k-tiles
        for (int i = t; i < 4096; i += 256) {
            int r = i >> 6, c = i & 63;
            tile[r][c] = W_hh[(size_t)(j0 + r) * 256 + k0 + c];
        }
        __syncthreads();
        for (int i = t; i < 4096; i += 256) {
            int r = i >> 6, c = i & 63;
            W_hh_T[(size_t)(k0 + r) * 1024 + j0 + c] = tile[c][r];
        }
    } else if (blk == 176) {
        // per-step bias: b_ih + b_hh + addr_emb[aid] @ W_addr.T  (W_ih cols 416..431)
        const int aids[7] = {0, 1, 4, 2, 3, 5, 6};
        for (int s = 0; s < 7; s++) {
            int aid = aids[s];
            for (int j = t; j < 1024; j += 256) {
                float v = b_ih[j] + b_hh[j];
                #pragma unroll
                for (int k = 0; k < 16; k++)
                    v += addr_emb[aid * 16 + k] * W_ih[(size_t)j * 432 + 416 + k];
                bias_all[s * 1024 + j] = v;
            }
        }
    } else if (blk == 177) {
        // pid_rows = pid_emb @ W_samp.T (3x1024), sid_rows (2x1024); W_ih cols 400..415
        for (int p = 0; p < 3; p++)
            for (int j = t; j < 1024; j += 256) {
                float v = 0.f;
                #pragma unroll
                for (int k = 0; k < 16; k++)
                    v += pid_emb[p * 16 + k] * W_ih[(size_t)j * 432 + 400 + k];
                pid_rows[p * 1024 + j] = v;
            }
        for (int p = 0; p < 2; p++)
            for (int j = t; j < 1024; j += 256) {
                float v = 0.f;
                #pragma unroll
                for (int k = 0; k < 16; k++)
                    v += sid_emb[p * 16 + k] * W_ih[(size_t)j * 432 + 400 + k];
                sid_rows[p * 1024 + j] = v;
            }
    } else {
        // transpose mlp_w2 (100x100) and mlp_w3 (16x100)
        for (int i = t; i < 10000; i += 256) {
            int o = i / 100, k = i % 100;
            w2t[k * 100 + o] = mlp_w2[i];
        }
        for (int i = t; i < 1600; i += 256) {
            int o = i / 100, k = i % 100;
            w3t[k * 16 + o] = mlp_w3[i];
        }
    }
}

// ---------------------------------------------------------------------------
// Conv encoder: one block per image, TWO 16-channel passes so LDS = 32 KB
// (5 blocks/CU, was 64 KB -> 2 blocks/CU). c1 stored bf16 with XOR swizzle
// col ^ ((r&2)<<3) ^ ((ch&3)<<2) to break the R+-2 same-bank pattern.
// conv2 accumulators persist in registers across passes; pool reuses LDS.
// ---------------------------------------------------------------------------
__global__ __launch_bounds__(256) void conv_kernel(
    const float* __restrict__ obs, const float* __restrict__ w1,
    const float* __restrict__ b1, const float* __restrict__ w2,
    const float* __restrict__ b2, float* __restrict__ obs_emb)
{
    __shared__ __hip_bfloat16 c1s[16 * 32 * 32];  // 32 KB, swizzled columns
    const int b = blockIdx.x;
    const int t = threadIdx.x;
    const float* og = obs + (size_t)b * 4096;

    // ---- conv2 per-thread constants (output position y,x on 16x16) ----
    const int y = t >> 4, x = t & 15;
    float acc[16];
    #pragma unroll
    for (int o = 0; o < 16; o++) acc[o] = b2[o];
    int Rv[3], Cv[3];
    float m9[9];
    {
        float rm[3], cm[3];
        #pragma unroll
        for (int d = 0; d < 3; d++) {
            int R = 2 * y - 1 + d;
            rm[d] = ((unsigned)R < 32u) ? 1.f : 0.f;
            Rv[d] = min(max(R, 0), 31);
            int C = 2 * x - 1 + d;
            cm[d] = ((unsigned)C < 32u) ? 1.f : 0.f;
            Cv[d] = min(max(C, 0), 31);
        }
        #pragma unroll
        for (int dy = 0; dy < 3; dy++)
            #pragma unroll
            for (int dx = 0; dx < 3; dx++) m9[dy * 3 + dx] = rm[dy] * cm[dx];
    }

    // ---- conv1 thread mapping: 16 ch x (8 col-groups of 4) x (2 row halves)
    const int c1c = t >> 4;          // channel within pass (0..15)
    const int lane = t & 15;
    const int x0 = (lane & 7) * 4;   // output cols x0..x0+3
    const int r0 = (lane >> 3) * 16; // output rows r0..r0+15

    for (int pass = 0; pass < 2; pass++) {
        if (pass) __syncthreads();  // pass-1 readers done before overwrite
        // conv1: 16 channels of this pass -> LDS (bf16, swizzled)
        {
            int ch = pass * 16 + c1c;
            float wv[9];
            #pragma unroll
            for (int k = 0; k < 9; k++) wv[k] = w1[ch * 9 + k];
            float bb = b1[ch];
            for (int r = r0; r < r0 + 16; r++) {
                float o4[4] = {bb, bb, bb, bb};
                #pragma unroll
                for (int dy = 0; dy < 3; dy++) {
                    int R = 2 * r - 1 + dy;
                    bool rok = (unsigned)R < 64u;
                    float in9[9];
                    #pragma unroll
                    for (int j = 0; j < 9; j++) {
                        int C = 2 * x0 - 1 + j;
                        in9[j] = (rok && (unsigned)C < 64u) ? og[R * 64 + C] : 0.f;
                    }
                    #pragma unroll
                    for (int xx = 0; xx < 4; xx++)
                        #pragma unroll
                        for (int dx = 0; dx < 3; dx++)
                            o4[xx] += wv[dy * 3 + dx] * in9[2 * xx + dx];
                }
                int sw = ((r & 2) << 3) ^ ((c1c & 3) << 2);
                __hip_bfloat16* dst = &c1s[(c1c * 32 + r) * 32 + (x0 ^ sw)];
                #pragma unroll
                for (int xx = 0; xx < 4; xx++)
                    dst[xx] = __float2bfloat16(fmaxf(o4[xx], 0.f));
            }
        }
        __syncthreads();
        // conv2: accumulate this pass's 16 input channels
        #pragma unroll 4
        for (int i = 0; i < 16; i++) {
            int ic = pass * 16 + i;
            float p[9];
            #pragma unroll
            for (int dy = 0; dy < 3; dy++) {
                int R = Rv[dy];
                int swr = ((R & 2) << 3) ^ ((i & 3) << 2);
                #pragma unroll
                for (int dx = 0; dx < 3; dx++) {
                    float v = __bfloat162float(c1s[(i * 32 + R) * 32 + (Cv[dx] ^ swr)]);
                    p[dy * 3 + dx] = m9[dy * 3 + dx] * v;
                }
            }
            // wave-uniform weight index -> scalar loads
            #pragma unroll
            for (int o = 0; o < 16; o++) {
                #pragma unroll
                for (int k = 0; k < 9; k++)
                    acc[o] += p[k] * w2[(o * 32 + ic) * 9 + k];
            }
        }
    }

    // relu -> LDS (reuse c1s as fp32 c2), then 3x3/9 avg pool -> obs_emb
    __syncthreads();
    float* c2f = (float*)c1s;  // 16*16*16 fp32 = 16 KB
    #pragma unroll
    for (int o = 0; o < 16; o++)
        c2f[(o * 16 + y) * 16 + x] = fmaxf(acc[o], 0.f);
    __syncthreads();
    for (int p = t; p < 400; p += 256) {
        int c = p / 25, rem = p % 25, py = rem / 5, px = rem % 5;
        float s = 0.f;
        #pragma unroll
        for (int dy = 0; dy < 3; dy++)
            #pragma unroll
            for (int dx = 0; dx < 3; dx++)
                s += c2f[(c * 16 + 3 * py + dy) * 16 + 3 * px + dx];
        obs_emb[(size_t)b * 400 + p] = s * (1.f / 9.f);
    }
}

// ---------------------------------------------------------------------------
// obs_part = obs_emb (B x 400) @ W_obs.T -> (B x 1024). M-tile 16, 512 thr.
// ---------------------------------------------------------------------------
__global__ __launch_bounds__(512) void obs_gemm(
    const float* __restrict__ A, const float* __restrict__ Wt,
    float* __restrict__ outp)
{
    __shared__ float as_t[400][20];  // transposed A tile, padded (b128-aligned)
    __shared__ float Ws[8 * 1024];
    const int t = threadIdx.x;
    const int u = t & 255;
    const int mh = t >> 8;
    const int b0 = blockIdx.x * 16;
    float acc[8][4];
    #pragma unroll
    for (int m = 0; m < 8; m++)
        #pragma unroll
        for (int g = 0; g < 4; g++) acc[m][g] = 0.f;

    for (int i = t; i < 16 * 400; i += 512) {
        int r = i / 400, c = i % 400;
        as_t[c][r] = A[(size_t)(b0 + r) * 400 + c];
    }
    for (int kt = 0; kt < 50; kt++) {
        __syncthreads();
        int k0 = kt * 8;
        #pragma unroll
        for (int i = 0; i < 4; i++) {
            int f = t + i * 512;
            int rr = f >> 8, cc = f & 255;
            ((float4*)Ws)[f] = ((const float4*)(Wt + (size_t)(k0 + rr) * 1024))[cc];
        }
        __syncthreads();
        #pragma unroll
        for (int kk = 0; kk < 8; kk++) {
            float w0 = Ws[kk * 1024 + u];
            float w1 = Ws[kk * 1024 + u + 256];
            float w2 = Ws[kk * 1024 + u + 512];
            float w3 = Ws[kk * 1024 + u + 768];
            const float4* hp = (const float4*)&as_t[k0 + kk][mh * 8];
            float4 ha = hp[0], hb = hp[1];
            float hv[8] = {ha.x, ha.y, ha.z, ha.w, hb.x, hb.y, hb.z, hb.w};
            #pragma unroll
            for (int m = 0; m < 8; m++) {
                acc[m][0] += hv[m] * w0;
                acc[m][1] += hv[m] * w1;
                acc[m][2] += hv[m] * w2;
                acc[m][3] += hv[m] * w3;
            }
        }
    }
    #pragma unroll
    for (int m = 0; m < 8; m++) {
        size_t row = b0 + mh * 8 + m;
        #pragma unroll
        for (int g = 0; g < 4; g++)
            outp[row * 1024 + u + 256 * g] = acc[m][g];
    }
}

// ---------------------------------------------------------------------------
// Fused LSTM step: g = obs_part + bias_s + samp + h@W_hh.T, elementwise,
// optional head into d_out. Thread t owns gates {u, u+256, u+512, u+768}.
// SAMP: 0 none, 1 gather(samp_rows, samp_idx), 2 rp0_emb@W_samp.T (K=16)
// HEAD: 0 none, 1 logits(HEAD_N), 2 rp-pair (exp + eps)
// ---------------------------------------------------------------------------
template <int SAMP, int HEAD, int HEAD_N, bool HAS_GEMM, bool STORE_RP>
__global__ __launch_bounds__(512) void lstm_step(
    const float* __restrict__ h_in, const float* __restrict__ c_in,
    float* __restrict__ h_out, float* __restrict__ c_out,
    const float* __restrict__ obs_part, const float* __restrict__ bias_s,
    const float* __restrict__ samp_rows, const int* __restrict__ samp_idx,
    const float* __restrict__ rp0_emb, const float* __restrict__ WsampT,
    const float* __restrict__ Wt,
    const float* __restrict__ head_w, const float* __restrict__ head_b,
    const float* __restrict__ eps, float* __restrict__ out, int out_off,
    float* __restrict__ rp0_store)
{
    __shared__ float hs_t[256][20];  // h_in tile transposed [k][m], padded
    __shared__ float Ws[8 * 1024];   // W_hh_T k-slab; reused for head h-tile
    const int t = threadIdx.x;
    const int u = t & 255;
    const int mh = t >> 8;  // row half: rows mh*8 .. mh*8+7
    const int b0 = blockIdx.x * 16;

    float acc[8][4];
    #pragma unroll
    for (int m = 0; m < 8; m++) {
        int row = b0 + mh * 8 + m;
        int si = (SAMP == 1) ? samp_idx[row] : 0;
        #pragma unroll
        for (int g = 0; g < 4; g++) {
            int j = u + 256 * g;
            float v = obs_part[(size_t)row * 1024 + j] + bias_s[j];
            if (SAMP == 1) v += samp_rows[si * 1024 + j];
            acc[m][g] = v;
        }
    }
    if (SAMP == 2) {
        #pragma unroll
        for (int m = 0; m < 8; m++) {
            int row = b0 + mh * 8 + m;
            #pragma unroll
            for (int k = 0; k < 16; k++) {
                float e = rp0_emb[(size_t)row * 16 + k];
                #pragma unroll
                for (int g = 0; g < 4; g++)
                    acc[m][g] += e * WsampT[k * 1024 + u + 256 * g];
            }
        }
    }

    if (HAS_GEMM) {
        for (int i = t; i < 4096; i += 512) {
            int r = i >> 8, c = i & 255;
            hs_t[c][r] = h_in[(size_t)(b0 + r) * 256 + c];
        }
        for (int kt = 0; kt < 32; kt++) {
            __syncthreads();
            int k0 = kt * 8;
            #pragma unroll
            for (int i = 0; i < 4; i++) {
                int f = t + i * 512;
                int rr = f >> 8, cc = f & 255;
                ((float4*)Ws)[f] = ((const float4*)(Wt + (size_t)(k0 + rr) * 1024))[cc];
            }
            __syncthreads();
            #pragma unroll
            for (int kk = 0; kk < 8; kk++) {
                float w0 = Ws[kk * 1024 + u];
                float w1 = Ws[kk * 1024 + u + 256];
                float w2 = Ws[kk * 1024 + u + 512];
                float w3 = Ws[kk * 1024 + u + 768];
                const float4* hp = (const float4*)&hs_t[k0 + kk][mh * 8];
                float4 ha = hp[0], hb = hp[1];
                float hv[8] = {ha.x, ha.y, ha.z, ha.w, hb.x, hb.y, hb.z, hb.w};
                #pragma unroll
                for (int m = 0; m < 8; m++) {
                    acc[m][0] += hv[m] * w0;
                    acc[m][1] += hv[m] * w1;
                    acc[m][2] += hv[m] * w2;
                    acc[m][3] += hv[m] * w3;
                }
            }
        }
    }

    // LSTM elementwise: i,f,g,o all in this thread's registers
    float hval[8];
    #pragma unroll
    for (int m = 0; m < 8; m++) {
        size_t row = b0 + mh * 8 + m;
        float ci = HAS_GEMM ? c_in[row * 256 + u] : 0.f;
        float gi = acc[m][0], gf = acc[m][1], gg = acc[m][2], go = acc[m][3];
        float c2 = sigf(gf) * ci + sigf(gi) * tanh_fast(gg);
        float hv = sigf(go) * tanh_fast(c2);
        c_out[row * 256 + u] = c2;
        h_out[row * 256 + u] = hv;
        hval[m] = hv;
    }

    if (HEAD != 0) {
        __syncthreads();  // done reading Ws/hs_t
        float* hsh = Ws;  // 16 x 256 h tile
        #pragma unroll
        for (int m = 0; m < 8; m++) hsh[(mh * 8 + m) * 256 + u] = hval[m];
        __syncthreads();
        if (HEAD == 1) {
            if (t < 16 * HEAD_N) {
                int m = t & 15, o = t >> 4;
                float s = head_b[o];
                for (int k = 0; k < 256; k++)
                    s += hsh[m * 256 + k] * head_w[o * 256 + k];
                out[(size_t)(b0 + m) * OUT_W + out_off + o] = s;
            }
        } else {
            if (t < 32) {
                int m = t & 15, o = t >> 4;  // o in {0,1}
                float sa = head_b[o], sb = head_b[o + 2];
                for (int k = 0; k < 256; k++) {
                    float h = hsh[m * 256 + k];
                    sa += h * head_w[o * 256 + k];
                    sb += h * head_w[(o + 2) * 256 + k];
                }
                float val = sa + __expf(sb) * eps[(size_t)(b0 + m) * 2 + o];
                out[(size_t)(b0 + m) * OUT_W + out_off + o] = val;
                if (STORE_RP) rp0_store[(size_t)(b0 + m) * 2 + o] = val;
            }
        }
    }
}

// ---------------------------------------------------------------------------
// MLP: rp0 (B x 2) -> 100 -> 100 -> rp0_emb (B x 16), one block per row
// ---------------------------------------------------------------------------
__global__ __launch_bounds__(128) void mlp_kernel(
    const float* __restrict__ rp0, const float* __restrict__ w1,
    const float* __restrict__ b1, const float* __restrict__ w2t,
    const float* __restrict__ b2, const float* __restrict__ w3t,
    const float* __restrict__ b3, float* __restrict__ emb)
{
    __shared__ float z1[100], z2[100];
    int row = blockIdx.x, t = threadIdx.x;
    float r0 = rp0[(size_t)row * 2], r1 = rp0[(size_t)row * 2 + 1];
    if (t < 100) z1[t] = tanh_fast(b1[t] + w1[t * 2] * r0 + w1[t * 2 + 1] * r1);
    __syncthreads();
    if (t < 100) {
        float s = b2[t];
        for (int k = 0; k < 100; k++) s += w2t[k * 100 + t] * z1[k];
        z2[t] = tanh_fast(s);
    }
    __syncthreads();
    if (t < 16) {
        float s = b3[t];
        for (int k = 0; k < 100; k++) s += w3t[k * 16 + t] * z2[k];
        emb[(size_t)row * 16 + t] = s;
    }
}

// ---------------------------------------------------------------------------
extern "C" void kernel_launch(void* const* d_in, const int* in_sizes, int n_in,
                              void* d_out, int out_size, void* d_ws, size_t ws_size,
                              hipStream_t stream)
{
    const float* obs        = (const float*)d_in[0];
    const int*   program_id = (const int*)d_in[1];
    const int*   shape_id   = (const int*)d_in[2];
    const int*   shape_id_0 = (const int*)d_in[3];
    const int*   shape_id_1 = (const int*)d_in[4];
    const float* eps_rp     = (const float*)d_in[5];
    const float* eps_rp0    = (const float*)d_in[6];
    const float* eps_rp1    = (const float*)d_in[7];
    const float* conv1_w    = (const float*)d_in[8];
    const float* conv1_b    = (const float*)d_in[9];
    const float* conv2_w    = (const float*)d_in[10];
    const float* conv2_b    = (const float*)d_in[11];
    const float* mlp_w1     = (const float*)d_in[12];
    const float* mlp_b1     = (const float*)d_in[13];
    const float* mlp_w2     = (const float*)d_in[14];
    const float* mlp_b2     = (const float*)d_in[15];
    const float* mlp_w3     = (const float*)d_in[16];
    const float* mlp_b3     = (const float*)d_in[17];
    const float* W_ih       = (const float*)d_in[18];
    const float* b_ih       = (const float*)d_in[19];
    const float* W_hh       = (const float*)d_in[20];
    const float* b_hh       = (const float*)d_in[21];
    const float* addr_emb   = (const float*)d_in[22];
    const float* pid_emb    = (const float*)d_in[23];
    const float* sid_emb    = (const float*)d_in[24];
    const float* pid_ext_w  = (const float*)d_in[25];
    const float* pid_ext_b  = (const float*)d_in[26];
    const float* sid_ext_w  = (const float*)d_in[27];
    const float* sid_ext_b  = (const float*)d_in[28];
    const float* rp_ext_w   = (const float*)d_in[29];
    const float* rp_ext_b   = (const float*)d_in[30];
    float* out = (float*)d_out;

    // workspace layout (floats)
    float* ws = (float*)d_ws;
    size_t off = 0;
    float* W_ih_T   = ws + off; off += 432 * 1024;
    float* W_hh_T   = ws + off; off += 256 * 1024;
    float* bias_all = ws + off; off += 7 * 1024;
    float* pid_rows = ws + off; off += 3 * 1024;
    float* sid_rows = ws + off; off += 2 * 1024;
    float* obs_emb  = ws + off; off += (size_t)BATCH * 400;
    float* obs_part = ws + off; off += (size_t)BATCH * 1024;
    float* h0 = ws + off; off += (size_t)BATCH * 256;
    float* c0 = ws + off; off += (size_t)BATCH * 256;
    float* h1 = ws + off; off += (size_t)BATCH * 256;
    float* c1 = ws + off; off += (size_t)BATCH * 256;
    float* rp0      = ws + off; off += (size_t)BATCH * 2;
    float* rp0_emb  = ws + off; off += (size_t)BATCH * 16;
    float* w2t = ws + off; off += 10000;
    float* w3t = ws + off; off += 1600;
    float* WsampT = W_ih_T + (size_t)400 * 1024;  // rows 400..415 of W_ih_T

    prep_kernel<<<179, 256, 0, stream>>>(W_ih, W_hh, b_ih, b_hh, addr_emb,
                                         pid_emb, sid_emb, mlp_w2, mlp_w3,
                                         W_ih_T, W_hh_T, bias_all, pid_rows,
                                         sid_rows, w2t, w3t);
    conv_kernel<<<BATCH, 256, 0, stream>>>(obs, conv1_w, conv1_b, conv2_w,
                                           conv2_b, obs_emb);
    obs_gemm<<<BATCH / 16, 512, 0, stream>>>(obs_emb, W_ih_T, obs_part);

    // step0 (aid 0): h=c=0, head pid_logits (3) -> cols 0..2
    lstm_step<0, 1, 3, false, false><<<BATCH / 16, 512, 0, stream>>>(
        nullptr, nullptr, h0, c0, obs_part, bias_all + 0 * 1024,
        nullptr, nullptr, nullptr, nullptr, nullptr,
        pid_ext_w, pid_ext_b, nullptr, out, 0, nullptr);
    // step1 (aid 1): samp=pid_rows[program_id], h0->h1; head sid -> cols 3..4
    lstm_step<1, 1, 2, true, false><<<BATCH / 16, 512, 0, stream>>>(
        h0, c0, h1, c1, obs_part, bias_all + 1 * 1024,
        pid_rows, program_id, nullptr, nullptr, W_hh_T,
        sid_ext_w, sid_ext_b, nullptr, out, 3, nullptr);
    // step2 (aid 4): samp=sid_rows[shape_id], h1->h1 in-place; head rp_b0 -> cols 5..6
    lstm_step<1, 2, 0, true, false><<<BATCH / 16, 512, 0, stream>>>(
        h1, c1, h1, c1, obs_part, bias_all + 2 * 1024,
        sid_rows, shape_id, nullptr, nullptr, W_hh_T,
        rp_ext_w, rp_ext_b, eps_rp, out, 5, nullptr);
    // step1b (aid 2): samp=pid_rows[program_id], h0->h0 in-place; head sid0 -> cols 7..8
    lstm_step<1, 1, 2, true, false><<<BATCH / 16, 512, 0, stream>>>(
        h0, c0, h0, c0, obs_part, bias_all + 3 * 1024,
        pid_rows, program_id, nullptr, nullptr, W_hh_T,
        sid_ext_w, sid_ext_b, nullptr, out, 7, nullptr);
    // step2b (aid 3): samp=sid_rows[shape_id_0]; head sid1 -> cols 9..10
    lstm_step<1, 1, 2, true, false><<<BATCH / 16, 512, 0, stream>>>(
        h0, c0, h0, c0, obs_part, bias_all + 4 * 1024,
        sid_rows, shape_id_0, nullptr, nullptr, W_hh_T,
        sid_ext_w, sid_ext_b, nullptr, out, 9, nullptr);
    // step3b (aid 5): samp=sid_rows[shape_id_1]; head rp0 -> cols 11..12 (+store)
    lstm_step<1, 2, 0, true, true><<<BATCH / 16, 512, 0, stream>>>(
        h0, c0, h0, c0, obs_part, bias_all + 5 * 1024,
        sid_rows, shape_id_1, nullptr, nullptr, W_hh_T,
        rp_ext_w, rp_ext_b, eps_rp0, out, 11, rp0);
    mlp_kernel<<<BATCH, 128, 0, stream>>>(rp0, mlp_w1, mlp_b1, w2t, mlp_b2,
                                          w3t, mlp_b3, rp0_emb);
    // step4b (aid 6): samp = rp0_emb @ W_samp.T; head rp1 -> cols 13..14
    lstm_step<2, 2, 0, true, false><<<BATCH / 16, 512, 0, stream>>>(
        h0, c0, h1, c1, obs_part, bias_all + 6 * 1024,
        nullptr, nullptr, rp0_emb, WsampT, W_hh_T,
        rp_ext_w, rp_ext_b, eps_rp1, out, 13, nullptr);
}

// Round 3
// 1203.150 us; speedup vs baseline: 1.1717x; 1.1717x over previous
//
#include <hip/hip_runtime.h>
#include <hip/hip_bf16.h>
#include <math.h>

#define BATCH 4096
#define HID 256
#define NG 1024   // 4*HID
#define OBS_D 400
#define OUT_W 15

__device__ __forceinline__ float sigf(float x) { return 1.0f / (1.0f + __expf(-x)); }
__device__ __forceinline__ float tanh_fast(float x) { return 1.0f - 2.0f / (__expf(2.0f * x) + 1.0f); }

// ---------------------------------------------------------------------------
// Prep: weight transposes + per-step fused biases + samp gather tables
// ---------------------------------------------------------------------------
__global__ __launch_bounds__(256) void prep_kernel(
    const float* __restrict__ W_ih, const float* __restrict__ W_hh,
    const float* __restrict__ b_ih, const float* __restrict__ b_hh,
    const float* __restrict__ addr_emb, const float* __restrict__ pid_emb,
    const float* __restrict__ sid_emb,
    const float* __restrict__ mlp_w2, const float* __restrict__ mlp_w3,
    float* __restrict__ W_ih_T, float* __restrict__ W_hh_T,
    float* __restrict__ bias_all, float* __restrict__ pid_rows,
    float* __restrict__ sid_rows, float* __restrict__ w2t, float* __restrict__ w3t)
{
    int blk = blockIdx.x, t = threadIdx.x;
    if (blk < 112) {
        // W_ih (1024x432) -> W_ih_T (432x1024), 64x64 tiles (16 j-tiles x 7 k-tiles)
        __shared__ float tile[64][65];
        int j0 = (blk & 15) * 64;
        int k0 = (blk >> 4) * 64;
        for (int i = t; i < 4096; i += 256) {
            int r = i >> 6, c = i & 63;
            int k = k0 + c;
            tile[r][c] = (k < 432) ? W_ih[(size_t)(j0 + r) * 432 + k] : 0.f;
        }
        __syncthreads();
        for (int i = t; i < 4096; i += 256) {
            int r = i >> 6, c = i & 63;
            int k = k0 + r;
            if (k < 432) W_ih_T[(size_t)k * 1024 + j0 + c] = tile[c][r];
        }
    } else if (blk < 176) {
        // W_hh (1024x256) -> W_hh_T (256x1024)
        __shared__ float tile[64][65];
        int bb = blk - 112;
        int j0 = (bb & 15) * 64;
        int k0 = (bb >> 4) * 64;  // 4 k-tiles
        for (int i = t; i < 4096; i += 256) {
            int r = i >> 6, c = i & 63;
            tile[r][c] = W_hh[(size_t)(j0 + r) * 256 + k0 + c];
        }
        __syncthreads();
        for (int i = t; i < 4096; i += 256) {
            int r = i >> 6, c = i & 63;
            W_hh_T[(size_t)(k0 + r) * 1024 + j0 + c] = tile[c][r];
        }
    } else if (blk == 176) {
        // per-step bias: b_ih + b_hh + addr_emb[aid] @ W_addr.T  (W_ih cols 416..431)
        const int aids[7] = {0, 1, 4, 2, 3, 5, 6};
        for (int s = 0; s < 7; s++) {
            int aid = aids[s];
            for (int j = t; j < 1024; j += 256) {
                float v = b_ih[j] + b_hh[j];
                #pragma unroll
                for (int k = 0; k < 16; k++)
                    v += addr_emb[aid * 16 + k] * W_ih[(size_t)j * 432 + 416 + k];
                bias_all[s * 1024 + j] = v;
            }
        }
    } else if (blk == 177) {
        // pid_rows = pid_emb @ W_samp.T (3x1024), sid_rows (2x1024); W_ih cols 400..415
        for (int p = 0; p < 3; p++)
            for (int j = t; j < 1024; j += 256) {
                float v = 0.f;
                #pragma unroll
                for (int k = 0; k < 16; k++)
                    v += pid_emb[p * 16 + k] * W_ih[(size_t)j * 432 + 400 + k];
                pid_rows[p * 1024 + j] = v;
            }
        for (int p = 0; p < 2; p++)
            for (int j = t; j < 1024; j += 256) {
                float v = 0.f;
                #pragma unroll
                for (int k = 0; k < 16; k++)
                    v += sid_emb[p * 16 + k] * W_ih[(size_t)j * 432 + 400 + k];
                sid_rows[p * 1024 + j] = v;
            }
    } else {
        // transpose mlp_w2 (100x100) and mlp_w3 (16x100)
        for (int i = t; i < 10000; i += 256) {
            int o = i / 100, k = i % 100;
            w2t[k * 100 + o] = mlp_w2[i];
        }
        for (int i = t; i < 1600; i += 256) {
            int o = i / 100, k = i % 100;
            w3t[k * 16 + o] = mlp_w3[i];
        }
    }
}

// ---------------------------------------------------------------------------
// Conv encoder, fully fused. One block per image.
// obs staged once into padded fp32 LDS [68][68] (halo=4, zeroed) -> each
// thread (y,x on 16x16 conv2 grid) holds its 7x8 obs patch in registers,
// computes conv1 3x3 patch per input channel in regs (w1/w2 wave-uniform ->
// SGPR operands), accumulates 16 conv2 outputs. No c1 in LDS, no bf16.
// Boundary semantics: obs halo is zero; conv2's zero-padding of c1 is
// enforced by masking c1 row 0 (y==0) / col 0 (x==0).
// ---------------------------------------------------------------------------
__global__ __launch_bounds__(256) void conv_kernel(
    const float* __restrict__ obs, const float* __restrict__ w1,
    const float* __restrict__ b1, const float* __restrict__ w2,
    const float* __restrict__ b2, float* __restrict__ obs_emb)
{
    __shared__ float sm[68 * 68];  // 18496 B
    const int b = blockIdx.x, t = threadIdx.x;
    const float* og = obs + (size_t)b * 4096;

    // zero whole buffer (borders matter), then stage interior
    #pragma unroll
    for (int i = 0; i < 5; i++) {
        int idx = t + i * 256;
        if (idx < 68 * 68 / 4) ((float4*)sm)[idx] = float4{0.f, 0.f, 0.f, 0.f};
    }
    __syncthreads();
    #pragma unroll
    for (int i = 0; i < 4; i++) {
        int idx4 = t + i * 256;           // 1024 float4 = 64x64 image
        int row = idx4 >> 4, c4 = idx4 & 15;
        float4 v = ((const float4*)og)[idx4];
        *((float4*)&sm[(row + 4) * 68 + 4 * c4 + 4]) = v;  // 16B-aligned
    }
    __syncthreads();

    const int y = t >> 4, x = t & 15;
    // 7x8 obs patch: buffer rows 4y+1..4y+7, cols 4x..4x+7 (obs 4y-3.., 4x-4..)
    float P[7][8];
    #pragma unroll
    for (int r = 0; r < 7; r++) {
        const float4* p = (const float4*)&sm[(4 * y + 1 + r) * 68 + 4 * x];
        float4 a = p[0], c = p[1];
        P[r][0] = a.x; P[r][1] = a.y; P[r][2] = a.z; P[r][3] = a.w;
        P[r][4] = c.x; P[r][5] = c.y; P[r][6] = c.z; P[r][7] = c.w;
    }

    float acc[16];
    #pragma unroll
    for (int o = 0; o < 16; o++) acc[o] = b2[o];
    const float mr0 = (y == 0) ? 0.f : 1.f;  // c1 row 2y-1 invalid at y==0
    const float mc0 = (x == 0) ? 0.f : 1.f;  // c1 col 2x-1 invalid at x==0

    #pragma unroll 4
    for (int ic = 0; ic < 32; ic++) {
        float c1p[9];
        const float* wv = w1 + ic * 9;   // wave-uniform -> SGPR
        float bb = b1[ic];
        #pragma unroll
        for (int j = 0; j < 3; j++) {
            #pragma unroll
            for (int i = 0; i < 3; i++) {
                float s = bb;
                #pragma unroll
                for (int dy = 0; dy < 3; dy++)
                    #pragma unroll
                    for (int dx = 0; dx < 3; dx++)
                        s += wv[dy * 3 + dx] * P[2 * j + dy][2 * i + dx + 1];
                s = fmaxf(s, 0.f);
                if (j == 0) s *= mr0;
                if (i == 0) s *= mc0;
                c1p[j * 3 + i] = s;
            }
        }
        const float* w2p = w2 + (size_t)ic * 9;  // wave-uniform
        #pragma unroll
        for (int o = 0; o < 16; o++) {
            #pragma unroll
            for (int k = 0; k < 9; k++)
                acc[o] += c1p[k] * w2p[o * 32 * 9 + k];
        }
    }

    // relu -> LDS (reuse sm as fp32 c2 [16][16][16]), then 3x3/9 avg pool
    __syncthreads();
    float* c2f = sm;
    #pragma unroll
    for (int o = 0; o < 16; o++)
        c2f[(o * 16 + y) * 16 + x] = fmaxf(acc[o], 0.f);
    __syncthreads();
    for (int p = t; p < 400; p += 256) {
        int c = p / 25, rem = p % 25, py = rem / 5, px = rem % 5;
        float s = 0.f;
        #pragma unroll
        for (int dy = 0; dy < 3; dy++)
            #pragma unroll
            for (int dx = 0; dx < 3; dx++)
                s += c2f[(c * 16 + 3 * py + dy) * 16 + 3 * px + dx];
        obs_emb[(size_t)b * 400 + p] = s * (1.f / 9.f);
    }
}

// ---------------------------------------------------------------------------
// obs_part = obs_emb (B x 400) @ W_obs.T -> (B x 1024). M-tile 16, 512 thr.
// ---------------------------------------------------------------------------
__global__ __launch_bounds__(512) void obs_gemm(
    const float* __restrict__ A, const float* __restrict__ Wt,
    float* __restrict__ outp)
{
    __shared__ float as_t[400][20];  // transposed A tile, padded (b128-aligned)
    __shared__ float Ws[8 * 1024];
    const int t = threadIdx.x;
    const int u = t & 255;
    const int mh = t >> 8;
    const int b0 = blockIdx.x * 16;
    float acc[8][4];
    #pragma unroll
    for (int m = 0; m < 8; m++)
        #pragma unroll
        for (int g = 0; g < 4; g++) acc[m][g] = 0.f;

    for (int i = t; i < 16 * 400; i += 512) {
        int r = i / 400, c = i % 400;
        as_t[c][r] = A[(size_t)(b0 + r) * 400 + c];
    }
    for (int kt = 0; kt < 50; kt++) {
        __syncthreads();
        int k0 = kt * 8;
        #pragma unroll
        for (int i = 0; i < 4; i++) {
            int f = t + i * 512;
            int rr = f >> 8, cc = f & 255;
            ((float4*)Ws)[f] = ((const float4*)(Wt + (size_t)(k0 + rr) * 1024))[cc];
        }
        __syncthreads();
        #pragma unroll
        for (int kk = 0; kk < 8; kk++) {
            float w0 = Ws[kk * 1024 + u];
            float w1 = Ws[kk * 1024 + u + 256];
            float w2 = Ws[kk * 1024 + u + 512];
            float w3 = Ws[kk * 1024 + u + 768];
            const float4* hp = (const float4*)&as_t[k0 + kk][mh * 8];
            float4 ha = hp[0], hb = hp[1];
            float hv[8] = {ha.x, ha.y, ha.z, ha.w, hb.x, hb.y, hb.z, hb.w};
            #pragma unroll
            for (int m = 0; m < 8; m++) {
                acc[m][0] += hv[m] * w0;
                acc[m][1] += hv[m] * w1;
                acc[m][2] += hv[m] * w2;
                acc[m][3] += hv[m] * w3;
            }
        }
    }
    #pragma unroll
    for (int m = 0; m < 8; m++) {
        size_t row = b0 + mh * 8 + m;
        #pragma unroll
        for (int g = 0; g < 4; g++)
            outp[row * 1024 + u + 256 * g] = acc[m][g];
    }
}

// ---------------------------------------------------------------------------
// Fused LSTM step: g = obs_part + bias_s + samp + h@W_hh.T, elementwise,
// optional head into d_out. Thread t owns gates {u, u+256, u+512, u+768}.
// SAMP: 0 none, 1 gather(samp_rows, samp_idx), 2 rp0_emb@W_samp.T (K=16)
// HEAD: 0 none, 1 logits(HEAD_N), 2 rp-pair (exp + eps)
// ---------------------------------------------------------------------------
template <int SAMP, int HEAD, int HEAD_N, bool HAS_GEMM, bool STORE_RP>
__global__ __launch_bounds__(512) void lstm_step(
    const float* __restrict__ h_in, const float* __restrict__ c_in,
    float* __restrict__ h_out, float* __restrict__ c_out,
    const float* __restrict__ obs_part, const float* __restrict__ bias_s,
    const float* __restrict__ samp_rows, const int* __restrict__ samp_idx,
    const float* __restrict__ rp0_emb, const float* __restrict__ WsampT,
    const float* __restrict__ Wt,
    const float* __restrict__ head_w, const float* __restrict__ head_b,
    const float* __restrict__ eps, float* __restrict__ out, int out_off,
    float* __restrict__ rp0_store)
{
    __shared__ float hs_t[256][20];  // h_in tile transposed [k][m], padded
    __shared__ float Ws[8 * 1024];   // W_hh_T k-slab; reused for head h-tile
    const int t = threadIdx.x;
    const int u = t & 255;
    const int mh = t >> 8;  // row half: rows mh*8 .. mh*8+7
    const int b0 = blockIdx.x * 16;

    float acc[8][4];
    #pragma unroll
    for (int m = 0; m < 8; m++) {
        int row = b0 + mh * 8 + m;
        int si = (SAMP == 1) ? samp_idx[row] : 0;
        #pragma unroll
        for (int g = 0; g < 4; g++) {
            int j = u + 256 * g;
            float v = obs_part[(size_t)row * 1024 + j] + bias_s[j];
            if (SAMP == 1) v += samp_rows[si * 1024 + j];
            acc[m][g] = v;
        }
    }
    if (SAMP == 2) {
        #pragma unroll
        for (int m = 0; m < 8; m++) {
            int row = b0 + mh * 8 + m;
            #pragma unroll
            for (int k = 0; k < 16; k++) {
                float e = rp0_emb[(size_t)row * 16 + k];
                #pragma unroll
                for (int g = 0; g < 4; g++)
                    acc[m][g] += e * WsampT[k * 1024 + u + 256 * g];
            }
        }
    }

    if (HAS_GEMM) {
        for (int i = t; i < 4096; i += 512) {
            int r = i >> 8, c = i & 255;
            hs_t[c][r] = h_in[(size_t)(b0 + r) * 256 + c];
        }
        for (int kt = 0; kt < 32; kt++) {
            __syncthreads();
            int k0 = kt * 8;
            #pragma unroll
            for (int i = 0; i < 4; i++) {
                int f = t + i * 512;
                int rr = f >> 8, cc = f & 255;
                ((float4*)Ws)[f] = ((const float4*)(Wt + (size_t)(k0 + rr) * 1024))[cc];
            }
            __syncthreads();
            #pragma unroll
            for (int kk = 0; kk < 8; kk++) {
                float w0 = Ws[kk * 1024 + u];
                float w1 = Ws[kk * 1024 + u + 256];
                float w2 = Ws[kk * 1024 + u + 512];
                float w3 = Ws[kk * 1024 + u + 768];
                const float4* hp = (const float4*)&hs_t[k0 + kk][mh * 8];
                float4 ha = hp[0], hb = hp[1];
                float hv[8] = {ha.x, ha.y, ha.z, ha.w, hb.x, hb.y, hb.z, hb.w};
                #pragma unroll
                for (int m = 0; m < 8; m++) {
                    acc[m][0] += hv[m] * w0;
                    acc[m][1] += hv[m] * w1;
                    acc[m][2] += hv[m] * w2;
                    acc[m][3] += hv[m] * w3;
                }
            }
        }
    }

    // LSTM elementwise: i,f,g,o all in this thread's registers
    float hval[8];
    #pragma unroll
    for (int m = 0; m < 8; m++) {
        size_t row = b0 + mh * 8 + m;
        float ci = HAS_GEMM ? c_in[row * 256 + u] : 0.f;
        float gi = acc[m][0], gf = acc[m][1], gg = acc[m][2], go = acc[m][3];
        float c2 = sigf(gf) * ci + sigf(gi) * tanh_fast(gg);
        float hv = sigf(go) * tanh_fast(c2);
        c_out[row * 256 + u] = c2;
        h_out[row * 256 + u] = hv;
        hval[m] = hv;
    }

    if (HEAD != 0) {
        __syncthreads();  // done reading Ws/hs_t
        float* hsh = Ws;  // 16 x 256 h tile
        #pragma unroll
        for (int m = 0; m < 8; m++) hsh[(mh * 8 + m) * 256 + u] = hval[m];
        __syncthreads();
        if (HEAD == 1) {
            if (t < 16 * HEAD_N) {
                int m = t & 15, o = t >> 4;
                float s = head_b[o];
                for (int k = 0; k < 256; k++)
                    s += hsh[m * 256 + k] * head_w[o * 256 + k];
                out[(size_t)(b0 + m) * OUT_W + out_off + o] = s;
            }
        } else {
            if (t < 32) {
                int m = t & 15, o = t >> 4;  // o in {0,1}
                float sa = head_b[o], sb = head_b[o + 2];
                for (int k = 0; k < 256; k++) {
                    float h = hsh[m * 256 + k];
                    sa += h * head_w[o * 256 + k];
                    sb += h * head_w[(o + 2) * 256 + k];
                }
                float val = sa + __expf(sb) * eps[(size_t)(b0 + m) * 2 + o];
                out[(size_t)(b0 + m) * OUT_W + out_off + o] = val;
                if (STORE_RP) rp0_store[(size_t)(b0 + m) * 2 + o] = val;
            }
        }
    }
}

// ---------------------------------------------------------------------------
// MLP: rp0 (B x 2) -> 100 -> 100 -> rp0_emb (B x 16), one block per row
// ---------------------------------------------------------------------------
__global__ __launch_bounds__(128) void mlp_kernel(
    const float* __restrict__ rp0, const float* __restrict__ w1,
    const float* __restrict__ b1, const float* __restrict__ w2t,
    const float* __restrict__ b2, const float* __restrict__ w3t,
    const float* __restrict__ b3, float* __restrict__ emb)
{
    __shared__ float z1[100], z2[100];
    int row = blockIdx.x, t = threadIdx.x;
    float r0 = rp0[(size_t)row * 2], r1 = rp0[(size_t)row * 2 + 1];
    if (t < 100) z1[t] = tanh_fast(b1[t] + w1[t * 2] * r0 + w1[t * 2 + 1] * r1);
    __syncthreads();
    if (t < 100) {
        float s = b2[t];
        for (int k = 0; k < 100; k++) s += w2t[k * 100 + t] * z1[k];
        z2[t] = tanh_fast(s);
    }
    __syncthreads();
    if (t < 16) {
        float s = b3[t];
        for (int k = 0; k < 100; k++) s += w3t[k * 16 + t] * z2[k];
        emb[(size_t)row * 16 + t] = s;
    }
}

// ---------------------------------------------------------------------------
extern "C" void kernel_launch(void* const* d_in, const int* in_sizes, int n_in,
                              void* d_out, int out_size, void* d_ws, size_t ws_size,
                              hipStream_t stream)
{
    const float* obs        = (const float*)d_in[0];
    const int*   program_id = (const int*)d_in[1];
    const int*   shape_id   = (const int*)d_in[2];
    const int*   shape_id_0 = (const int*)d_in[3];
    const int*   shape_id_1 = (const int*)d_in[4];
    const float* eps_rp     = (const float*)d_in[5];
    const float* eps_rp0    = (const float*)d_in[6];
    const float* eps_rp1    = (const float*)d_in[7];
    const float* conv1_w    = (const float*)d_in[8];
    const float* conv1_b    = (const float*)d_in[9];
    const float* conv2_w    = (const float*)d_in[10];
    const float* conv2_b    = (const float*)d_in[11];
    const float* mlp_w1     = (const float*)d_in[12];
    const float* mlp_b1     = (const float*)d_in[13];
    const float* mlp_w2     = (const float*)d_in[14];
    const float* mlp_b2     = (const float*)d_in[15];
    const float* mlp_w3     = (const float*)d_in[16];
    const float* mlp_b3     = (const float*)d_in[17];
    const float* W_ih       = (const float*)d_in[18];
    const float* b_ih       = (const float*)d_in[19];
    const float* W_hh       = (const float*)d_in[20];
    const float* b_hh       = (const float*)d_in[21];
    const float* addr_emb   = (const float*)d_in[22];
    const float* pid_emb    = (const float*)d_in[23];
    const float* sid_emb    = (const float*)d_in[24];
    const float* pid_ext_w  = (const float*)d_in[25];
    const float* pid_ext_b  = (const float*)d_in[26];
    const float* sid_ext_w  = (const float*)d_in[27];
    const float* sid_ext_b  = (const float*)d_in[28];
    const float* rp_ext_w   = (const float*)d_in[29];
    const float* rp_ext_b   = (const float*)d_in[30];
    float* out = (float*)d_out;

    // workspace layout (floats)
    float* ws = (float*)d_ws;
    size_t off = 0;
    float* W_ih_T   = ws + off; off += 432 * 1024;
    float* W_hh_T   = ws + off; off += 256 * 1024;
    float* bias_all = ws + off; off += 7 * 1024;
    float* pid_rows = ws + off; off += 3 * 1024;
    float* sid_rows = ws + off; off += 2 * 1024;
    float* obs_emb  = ws + off; off += (size_t)BATCH * 400;
    float* obs_part = ws + off; off += (size_t)BATCH * 1024;
    float* h0 = ws + off; off += (size_t)BATCH * 256;
    float* c0 = ws + off; off += (size_t)BATCH * 256;
    float* h1 = ws + off; off += (size_t)BATCH * 256;
    float* c1 = ws + off; off += (size_t)BATCH * 256;
    float* rp0      = ws + off; off += (size_t)BATCH * 2;
    float* rp0_emb  = ws + off; off += (size_t)BATCH * 16;
    float* w2t = ws + off; off += 10000;
    float* w3t = ws + off; off += 1600;
    float* WsampT = W_ih_T + (size_t)400 * 1024;  // rows 400..415 of W_ih_T

    prep_kernel<<<179, 256, 0, stream>>>(W_ih, W_hh, b_ih, b_hh, addr_emb,
                                         pid_emb, sid_emb, mlp_w2, mlp_w3,
                                         W_ih_T, W_hh_T, bias_all, pid_rows,
                                         sid_rows, w2t, w3t);
    conv_kernel<<<BATCH, 256, 0, stream>>>(obs, conv1_w, conv1_b, conv2_w,
                                           conv2_b, obs_emb);
    obs_gemm<<<BATCH / 16, 512, 0, stream>>>(obs_emb, W_ih_T, obs_part);

    // step0 (aid 0): h=c=0, head pid_logits (3) -> cols 0..2
    lstm_step<0, 1, 3, false, false><<<BATCH / 16, 512, 0, stream>>>(
        nullptr, nullptr, h0, c0, obs_part, bias_all + 0 * 1024,
        nullptr, nullptr, nullptr, nullptr, nullptr,
        pid_ext_w, pid_ext_b, nullptr, out, 0, nullptr);
    // step1 (aid 1): samp=pid_rows[program_id], h0->h1; head sid -> cols 3..4
    lstm_step<1, 1, 2, true, false><<<BATCH / 16, 512, 0, stream>>>(
        h0, c0, h1, c1, obs_part, bias_all + 1 * 1024,
        pid_rows, program_id, nullptr, nullptr, W_hh_T,
        sid_ext_w, sid_ext_b, nullptr, out, 3, nullptr);
    // step2 (aid 4): samp=sid_rows[shape_id], h1->h1 in-place; head rp_b0 -> cols 5..6
    lstm_step<1, 2, 0, true, false><<<BATCH / 16, 512, 0, stream>>>(
        h1, c1, h1, c1, obs_part, bias_all + 2 * 1024,
        sid_rows, shape_id, nullptr, nullptr, W_hh_T,
        rp_ext_w, rp_ext_b, eps_rp, out, 5, nullptr);
    // step1b (aid 2): samp=pid_rows[program_id], h0->h0 in-place; head sid0 -> cols 7..8
    lstm_step<1, 1, 2, true, false><<<BATCH / 16, 512, 0, stream>>>(
        h0, c0, h0, c0, obs_part, bias_all + 3 * 1024,
        pid_rows, program_id, nullptr, nullptr, W_hh_T,
        sid_ext_w, sid_ext_b, nullptr, out, 7, nullptr);
    // step2b (aid 3): samp=sid_rows[shape_id_0]; head sid1 -> cols 9..10
    lstm_step<1, 1, 2, true, false><<<BATCH / 16, 512, 0, stream>>>(
        h0, c0, h0, c0, obs_part, bias_all + 4 * 1024,
        sid_rows, shape_id_0, nullptr, nullptr, W_hh_T,
        sid_ext_w, sid_ext_b, nullptr, out, 9, nullptr);
    // step3b (aid 5): samp=sid_rows[shape_id_1]; head rp0 -> cols 11..12 (+store)
    lstm_step<1, 2, 0, true, true><<<BATCH / 16, 512, 0, stream>>>(
        h0, c0, h0, c0, obs_part, bias_all + 5 * 1024,
        sid_rows, shape_id_1, nullptr, nullptr, W_hh_T,
        rp_ext_w, rp_ext_b, eps_rp0, out, 11, rp0);
    mlp_kernel<<<BATCH, 128, 0, stream>>>(rp0, mlp_w1, mlp_b1, w2t, mlp_b2,
                                          w3t, mlp_b3, rp0_emb);
    // step4b (aid 6): samp = rp0_emb @ W_samp.T; head rp1 -> cols 13..14
    lstm_step<2, 2, 0, true, false><<<BATCH / 16, 512, 0, stream>>>(
        h0, c0, h1, c1, obs_part, bias_all + 6 * 1024,
        nullptr, nullptr, rp0_emb, WsampT, W_hh_T,
        rp_ext_w, rp_ext_b, eps_rp1, out, 13, nullptr);
}

// Round 4
// 909.032 us; speedup vs baseline: 1.5508x; 1.3236x over previous
//
#include <hip/hip_runtime.h>
#include <hip/hip_bf16.h>
#include <math.h>

#define BATCH 4096
#define HID 256
#define NG 1024   // 4*HID
#define OBS_D 400
#define OUT_W 15

__device__ __forceinline__ float sigf(float x) { return 1.0f / (1.0f + __expf(-x)); }
__device__ __forceinline__ float tanh_fast(float x) { return 1.0f - 2.0f / (__expf(2.0f * x) + 1.0f); }

// ---------------------------------------------------------------------------
// Prep: weight transposes + per-step fused biases + samp gather tables
// + packed conv weights: w1p [ic][12] (9 w + bias), w2p [ic][oc][12]
// ---------------------------------------------------------------------------
__global__ __launch_bounds__(256) void prep_kernel(
    const float* __restrict__ W_ih, const float* __restrict__ W_hh,
    const float* __restrict__ b_ih, const float* __restrict__ b_hh,
    const float* __restrict__ addr_emb, const float* __restrict__ pid_emb,
    const float* __restrict__ sid_emb,
    const float* __restrict__ mlp_w2, const float* __restrict__ mlp_w3,
    const float* __restrict__ conv1_w, const float* __restrict__ conv1_b,
    const float* __restrict__ conv2_w,
    float* __restrict__ W_ih_T, float* __restrict__ W_hh_T,
    float* __restrict__ bias_all, float* __restrict__ pid_rows,
    float* __restrict__ sid_rows, float* __restrict__ w2t, float* __restrict__ w3t,
    float* __restrict__ w1p, float* __restrict__ w2p)
{
    int blk = blockIdx.x, t = threadIdx.x;
    if (blk < 112) {
        // W_ih (1024x432) -> W_ih_T (432x1024), 64x64 tiles (16 j-tiles x 7 k-tiles)
        __shared__ float tile[64][65];
        int j0 = (blk & 15) * 64;
        int k0 = (blk >> 4) * 64;
        for (int i = t; i < 4096; i += 256) {
            int r = i >> 6, c = i & 63;
            int k = k0 + c;
            tile[r][c] = (k < 432) ? W_ih[(size_t)(j0 + r) * 432 + k] : 0.f;
        }
        __syncthreads();
        for (int i = t; i < 4096; i += 256) {
            int r = i >> 6, c = i & 63;
            int k = k0 + r;
            if (k < 432) W_ih_T[(size_t)k * 1024 + j0 + c] = tile[c][r];
        }
    } else if (blk < 176) {
        // W_hh (1024x256) -> W_hh_T (256x1024)
        __shared__ float tile[64][65];
        int bb = blk - 112;
        int j0 = (bb & 15) * 64;
        int k0 = (bb >> 4) * 64;  // 4 k-tiles
        for (int i = t; i < 4096; i += 256) {
            int r = i >> 6, c = i & 63;
            tile[r][c] = W_hh[(size_t)(j0 + r) * 256 + k0 + c];
        }
        __syncthreads();
        for (int i = t; i < 4096; i += 256) {
            int r = i >> 6, c = i & 63;
            W_hh_T[(size_t)(k0 + r) * 1024 + j0 + c] = tile[c][r];
        }
    } else if (blk == 176) {
        // per-step bias: b_ih + b_hh + addr_emb[aid] @ W_addr.T  (W_ih cols 416..431)
        const int aids[7] = {0, 1, 4, 2, 3, 5, 6};
        for (int s = 0; s < 7; s++) {
            int aid = aids[s];
            for (int j = t; j < 1024; j += 256) {
                float v = b_ih[j] + b_hh[j];
                #pragma unroll
                for (int k = 0; k < 16; k++)
                    v += addr_emb[aid * 16 + k] * W_ih[(size_t)j * 432 + 416 + k];
                bias_all[s * 1024 + j] = v;
            }
        }
    } else if (blk == 177) {
        // pid_rows = pid_emb @ W_samp.T (3x1024), sid_rows (2x1024); W_ih cols 400..415
        for (int p = 0; p < 3; p++)
            for (int j = t; j < 1024; j += 256) {
                float v = 0.f;
                #pragma unroll
                for (int k = 0; k < 16; k++)
                    v += pid_emb[p * 16 + k] * W_ih[(size_t)j * 432 + 400 + k];
                pid_rows[p * 1024 + j] = v;
            }
        for (int p = 0; p < 2; p++)
            for (int j = t; j < 1024; j += 256) {
                float v = 0.f;
                #pragma unroll
                for (int k = 0; k < 16; k++)
                    v += sid_emb[p * 16 + k] * W_ih[(size_t)j * 432 + 400 + k];
                sid_rows[p * 1024 + j] = v;
            }
    } else if (blk == 178) {
        // transpose mlp_w2 (100x100) and mlp_w3 (16x100)
        for (int i = t; i < 10000; i += 256) {
            int o = i / 100, k = i % 100;
            w2t[k * 100 + o] = mlp_w2[i];
        }
        for (int i = t; i < 1600; i += 256) {
            int o = i / 100, k = i % 100;
            w3t[k * 16 + o] = mlp_w3[i];
        }
    } else {
        // pack conv weights
        // w1p[ic*12 + k] = conv1_w[ic*9+k] (k<9), [ic*12+9] = conv1_b[ic]
        for (int i = t; i < 384; i += 256) {
            int ic = i / 12, k = i % 12;
            float v = 0.f;
            if (k < 9) v = conv1_w[ic * 9 + k];
            else if (k == 9) v = conv1_b[ic];
            w1p[i] = v;
        }
        // w2p[ic*192 + oc*12 + k] = conv2_w[(oc*32+ic)*9 + k] (k<9)
        for (int i = t; i < 6144; i += 256) {
            int ic = i / 192, rem = i % 192, oc = rem / 12, k = rem % 12;
            w2p[i] = (k < 9) ? conv2_w[(size_t)(oc * 32 + ic) * 9 + k] : 0.f;
        }
    }
}

// ---------------------------------------------------------------------------
// Conv encoder, fully fused, LDS-broadcast weights. One block per image.
// obs staged once into padded fp32 LDS [68][68] (halo=4, zeroed); packed
// conv weights staged into LDS and read at wave-uniform addresses
// (broadcast, ds_read_b128-aligned, zero VALU address math after unroll).
// Thread (y,x) on the 16x16 conv2 grid keeps its 7x8 obs patch in regs,
// computes the conv1 3x3 patch per input channel in regs, accumulates 16
// conv2 outputs. Boundary: obs halo zero; conv2 zero-padding via masks.
// LDS total 44608 B -> 3 blocks/CU; launch_bounds(256,3) -> ~170 VGPR cap.
// ---------------------------------------------------------------------------
__global__ __launch_bounds__(256, 3) void conv_kernel(
    const float* __restrict__ obs, const float* __restrict__ w1p,
    const float* __restrict__ w2p, const float* __restrict__ b2,
    float* __restrict__ obs_emb)
{
    __shared__ float sm[68 * 68];      // 18496 B
    __shared__ float w2s[32 * 192];    // 24576 B  [ic][oc][12]
    __shared__ float w1s[32 * 12];     // 1536 B   [ic][12]
    const int b = blockIdx.x, t = threadIdx.x;
    const float* og = obs + (size_t)b * 4096;

    // start obs loads early (into regs), stage weights + zero sm meanwhile
    float4 ov[4];
    #pragma unroll
    for (int i = 0; i < 4; i++) ov[i] = ((const float4*)og)[t + i * 256];

    #pragma unroll
    for (int i = 0; i < 5; i++) {
        int idx = t + i * 256;
        if (idx < 68 * 68 / 4) ((float4*)sm)[idx] = float4{0.f, 0.f, 0.f, 0.f};
    }
    #pragma unroll
    for (int i = 0; i < 6; i++)
        ((float4*)w2s)[t + i * 256] = ((const float4*)w2p)[t + i * 256];
    if (t < 96) ((float4*)w1s)[t] = ((const float4*)w1p)[t];
    __syncthreads();
    #pragma unroll
    for (int i = 0; i < 4; i++) {
        int idx4 = t + i * 256;           // 1024 float4 = 64x64 image
        int row = idx4 >> 4, c4 = idx4 & 15;
        *((float4*)&sm[(row + 4) * 68 + 4 * c4 + 4]) = ov[i];
    }
    __syncthreads();

    const int y = t >> 4, x = t & 15;
    // 7x8 obs patch: buffer rows 4y+1..4y+7, cols 4x..4x+7
    float P[7][8];
    #pragma unroll
    for (int r = 0; r < 7; r++) {
        const float4* p = (const float4*)&sm[(4 * y + 1 + r) * 68 + 4 * x];
        float4 a = p[0], c = p[1];
        P[r][0] = a.x; P[r][1] = a.y; P[r][2] = a.z; P[r][3] = a.w;
        P[r][4] = c.x; P[r][5] = c.y; P[r][6] = c.z; P[r][7] = c.w;
    }

    float acc[16];
    #pragma unroll
    for (int o = 0; o < 16; o++) acc[o] = b2[o];
    const float mr0 = (y == 0) ? 0.f : 1.f;  // c1 row 2y-1 invalid at y==0
    const float mc0 = (x == 0) ? 0.f : 1.f;  // c1 col 2x-1 invalid at x==0

    #pragma unroll 4
    for (int ic = 0; ic < 32; ic++) {
        // conv1 weights + bias from LDS (wave-uniform -> broadcast)
        const float* q = &w1s[ic * 12];
        float4 qa = *(const float4*)q;
        float4 qb = *(const float4*)(q + 4);
        float w8 = q[8], bb = q[9];
        float wv[9] = {qa.x, qa.y, qa.z, qa.w, qb.x, qb.y, qb.z, qb.w, w8};

        float c1p[9];
        #pragma unroll
        for (int j = 0; j < 3; j++) {
            #pragma unroll
            for (int i = 0; i < 3; i++) {
                float s = bb;
                #pragma unroll
                for (int dy = 0; dy < 3; dy++)
                    #pragma unroll
                    for (int dx = 0; dx < 3; dx++)
                        s += wv[dy * 3 + dx] * P[2 * j + dy][2 * i + dx + 1];
                s = fmaxf(s, 0.f);
                if (j == 0) s *= mr0;
                if (i == 0) s *= mc0;
                c1p[j * 3 + i] = s;
            }
        }
        // conv2: weights from LDS, broadcast, 16B-aligned
        #pragma unroll
        for (int o = 0; o < 16; o++) {
            const float* wp = &w2s[ic * 192 + o * 12];
            float4 wa = *(const float4*)wp;
            float4 wb = *(const float4*)(wp + 4);
            float w8b = wp[8];
            acc[o] += c1p[0] * wa.x + c1p[1] * wa.y + c1p[2] * wa.z +
                      c1p[3] * wa.w + c1p[4] * wb.x + c1p[5] * wb.y +
                      c1p[6] * wb.z + c1p[7] * wb.w + c1p[8] * w8b;
        }
    }

    // relu -> LDS (reuse sm as fp32 c2 [16][16][16]), then 3x3/9 avg pool
    __syncthreads();
    float* c2f = sm;
    #pragma unroll
    for (int o = 0; o < 16; o++)
        c2f[(o * 16 + y) * 16 + x] = fmaxf(acc[o], 0.f);
    __syncthreads();
    for (int p = t; p < 400; p += 256) {
        int c = p / 25, rem = p % 25, py = rem / 5, px = rem % 5;
        float s = 0.f;
        #pragma unroll
        for (int dy = 0; dy < 3; dy++)
            #pragma unroll
            for (int dx = 0; dx < 3; dx++)
                s += c2f[(c * 16 + 3 * py + dy) * 16 + 3 * px + dx];
        obs_emb[(size_t)b * 400 + p] = s * (1.f / 9.f);
    }
}

// ---------------------------------------------------------------------------
// obs_part = obs_emb (B x 400) @ W_obs.T -> (B x 1024). M-tile 16, 512 thr.
// ---------------------------------------------------------------------------
__global__ __launch_bounds__(512) void obs_gemm(
    const float* __restrict__ A, const float* __restrict__ Wt,
    float* __restrict__ outp)
{
    __shared__ float as_t[400][20];  // transposed A tile, padded (b128-aligned)
    __shared__ float Ws[8 * 1024];
    const int t = threadIdx.x;
    const int u = t & 255;
    const int mh = t >> 8;
    const int b0 = blockIdx.x * 16;
    float acc[8][4];
    #pragma unroll
    for (int m = 0; m < 8; m++)
        #pragma unroll
        for (int g = 0; g < 4; g++) acc[m][g] = 0.f;

    for (int i = t; i < 16 * 400; i += 512) {
        int r = i / 400, c = i % 400;
        as_t[c][r] = A[(size_t)(b0 + r) * 400 + c];
    }
    for (int kt = 0; kt < 50; kt++) {
        __syncthreads();
        int k0 = kt * 8;
        #pragma unroll
        for (int i = 0; i < 4; i++) {
            int f = t + i * 512;
            int rr = f >> 8, cc = f & 255;
            ((float4*)Ws)[f] = ((const float4*)(Wt + (size_t)(k0 + rr) * 1024))[cc];
        }
        __syncthreads();
        #pragma unroll
        for (int kk = 0; kk < 8; kk++) {
            float w0 = Ws[kk * 1024 + u];
            float w1 = Ws[kk * 1024 + u + 256];
            float w2 = Ws[kk * 1024 + u + 512];
            float w3 = Ws[kk * 1024 + u + 768];
            const float4* hp = (const float4*)&as_t[k0 + kk][mh * 8];
            float4 ha = hp[0], hb = hp[1];
            float hv[8] = {ha.x, ha.y, ha.z, ha.w, hb.x, hb.y, hb.z, hb.w};
            #pragma unroll
            for (int m = 0; m < 8; m++) {
                acc[m][0] += hv[m] * w0;
                acc[m][1] += hv[m] * w1;
                acc[m][2] += hv[m] * w2;
                acc[m][3] += hv[m] * w3;
            }
        }
    }
    #pragma unroll
    for (int m = 0; m < 8; m++) {
        size_t row = b0 + mh * 8 + m;
        #pragma unroll
        for (int g = 0; g < 4; g++)
            outp[row * 1024 + u + 256 * g] = acc[m][g];
    }
}

// ---------------------------------------------------------------------------
// Fused LSTM step: g = obs_part + bias_s + samp + h@W_hh.T, elementwise,
// optional head into d_out. Thread t owns gates {u, u+256, u+512, u+768}.
// SAMP: 0 none, 1 gather(samp_rows, samp_idx), 2 rp0_emb@W_samp.T (K=16)
// HEAD: 0 none, 1 logits(HEAD_N), 2 rp-pair (exp + eps)
// ---------------------------------------------------------------------------
template <int SAMP, int HEAD, int HEAD_N, bool HAS_GEMM, bool STORE_RP>
__global__ __launch_bounds__(512) void lstm_step(
    const float* __restrict__ h_in, const float* __restrict__ c_in,
    float* __restrict__ h_out, float* __restrict__ c_out,
    const float* __restrict__ obs_part, const float* __restrict__ bias_s,
    const float* __restrict__ samp_rows, const int* __restrict__ samp_idx,
    const float* __restrict__ rp0_emb, const float* __restrict__ WsampT,
    const float* __restrict__ Wt,
    const float* __restrict__ head_w, const float* __restrict__ head_b,
    const float* __restrict__ eps, float* __restrict__ out, int out_off,
    float* __restrict__ rp0_store)
{
    __shared__ float hs_t[256][20];  // h_in tile transposed [k][m], padded
    __shared__ float Ws[8 * 1024];   // W_hh_T k-slab; reused for head h-tile
    const int t = threadIdx.x;
    const int u = t & 255;
    const int mh = t >> 8;  // row half: rows mh*8 .. mh*8+7
    const int b0 = blockIdx.x * 16;

    float acc[8][4];
    #pragma unroll
    for (int m = 0; m < 8; m++) {
        int row = b0 + mh * 8 + m;
        int si = (SAMP == 1) ? samp_idx[row] : 0;
        #pragma unroll
        for (int g = 0; g < 4; g++) {
            int j = u + 256 * g;
            float v = obs_part[(size_t)row * 1024 + j] + bias_s[j];
            if (SAMP == 1) v += samp_rows[si * 1024 + j];
            acc[m][g] = v;
        }
    }
    if (SAMP == 2) {
        #pragma unroll
        for (int m = 0; m < 8; m++) {
            int row = b0 + mh * 8 + m;
            #pragma unroll
            for (int k = 0; k < 16; k++) {
                float e = rp0_emb[(size_t)row * 16 + k];
                #pragma unroll
                for (int g = 0; g < 4; g++)
                    acc[m][g] += e * WsampT[k * 1024 + u + 256 * g];
            }
        }
    }

    if (HAS_GEMM) {
        for (int i = t; i < 4096; i += 512) {
            int r = i >> 8, c = i & 255;
            hs_t[c][r] = h_in[(size_t)(b0 + r) * 256 + c];
        }
        for (int kt = 0; kt < 32; kt++) {
            __syncthreads();
            int k0 = kt * 8;
            #pragma unroll
            for (int i = 0; i < 4; i++) {
                int f = t + i * 512;
                int rr = f >> 8, cc = f & 255;
                ((float4*)Ws)[f] = ((const float4*)(Wt + (size_t)(k0 + rr) * 1024))[cc];
            }
            __syncthreads();
            #pragma unroll
            for (int kk = 0; kk < 8; kk++) {
                float w0 = Ws[kk * 1024 + u];
                float w1 = Ws[kk * 1024 + u + 256];
                float w2 = Ws[kk * 1024 + u + 512];
                float w3 = Ws[kk * 1024 + u + 768];
                const float4* hp = (const float4*)&hs_t[k0 + kk][mh * 8];
                float4 ha = hp[0], hb = hp[1];
                float hv[8] = {ha.x, ha.y, ha.z, ha.w, hb.x, hb.y, hb.z, hb.w};
                #pragma unroll
                for (int m = 0; m < 8; m++) {
                    acc[m][0] += hv[m] * w0;
                    acc[m][1] += hv[m] * w1;
                    acc[m][2] += hv[m] * w2;
                    acc[m][3] += hv[m] * w3;
                }
            }
        }
    }

    // LSTM elementwise: i,f,g,o all in this thread's registers
    float hval[8];
    #pragma unroll
    for (int m = 0; m < 8; m++) {
        size_t row = b0 + mh * 8 + m;
        float ci = HAS_GEMM ? c_in[row * 256 + u] : 0.f;
        float gi = acc[m][0], gf = acc[m][1], gg = acc[m][2], go = acc[m][3];
        float c2 = sigf(gf) * ci + sigf(gi) * tanh_fast(gg);
        float hv = sigf(go) * tanh_fast(c2);
        c_out[row * 256 + u] = c2;
        h_out[row * 256 + u] = hv;
        hval[m] = hv;
    }

    if (HEAD != 0) {
        __syncthreads();  // done reading Ws/hs_t
        float* hsh = Ws;  // 16 x 256 h tile
        #pragma unroll
        for (int m = 0; m < 8; m++) hsh[(mh * 8 + m) * 256 + u] = hval[m];
        __syncthreads();
        if (HEAD == 1) {
            if (t < 16 * HEAD_N) {
                int m = t & 15, o = t >> 4;
                float s = head_b[o];
                for (int k = 0; k < 256; k++)
                    s += hsh[m * 256 + k] * head_w[o * 256 + k];
                out[(size_t)(b0 + m) * OUT_W + out_off + o] = s;
            }
        } else {
            if (t < 32) {
                int m = t & 15, o = t >> 4;  // o in {0,1}
                float sa = head_b[o], sb = head_b[o + 2];
                for (int k = 0; k < 256; k++) {
                    float h = hsh[m * 256 + k];
                    sa += h * head_w[o * 256 + k];
                    sb += h * head_w[(o + 2) * 256 + k];
                }
                float val = sa + __expf(sb) * eps[(size_t)(b0 + m) * 2 + o];
                out[(size_t)(b0 + m) * OUT_W + out_off + o] = val;
                if (STORE_RP) rp0_store[(size_t)(b0 + m) * 2 + o] = val;
            }
        }
    }
}

// ---------------------------------------------------------------------------
// MLP: rp0 (B x 2) -> 100 -> 100 -> rp0_emb (B x 16), one block per row
// ---------------------------------------------------------------------------
__global__ __launch_bounds__(128) void mlp_kernel(
    const float* __restrict__ rp0, const float* __restrict__ w1,
    const float* __restrict__ b1, const float* __restrict__ w2t,
    const float* __restrict__ b2, const float* __restrict__ w3t,
    const float* __restrict__ b3, float* __restrict__ emb)
{
    __shared__ float z1[100], z2[100];
    int row = blockIdx.x, t = threadIdx.x;
    float r0 = rp0[(size_t)row * 2], r1 = rp0[(size_t)row * 2 + 1];
    if (t < 100) z1[t] = tanh_fast(b1[t] + w1[t * 2] * r0 + w1[t * 2 + 1] * r1);
    __syncthreads();
    if (t < 100) {
        float s = b2[t];
        for (int k = 0; k < 100; k++) s += w2t[k * 100 + t] * z1[k];
        z2[t] = tanh_fast(s);
    }
    __syncthreads();
    if (t < 16) {
        float s = b3[t];
        for (int k = 0; k < 100; k++) s += w3t[k * 16 + t] * z2[k];
        emb[(size_t)row * 16 + t] = s;
    }
}

// ---------------------------------------------------------------------------
extern "C" void kernel_launch(void* const* d_in, const int* in_sizes, int n_in,
                              void* d_out, int out_size, void* d_ws, size_t ws_size,
                              hipStream_t stream)
{
    const float* obs        = (const float*)d_in[0];
    const int*   program_id = (const int*)d_in[1];
    const int*   shape_id   = (const int*)d_in[2];
    const int*   shape_id_0 = (const int*)d_in[3];
    const int*   shape_id_1 = (const int*)d_in[4];
    const float* eps_rp     = (const float*)d_in[5];
    const float* eps_rp0    = (const float*)d_in[6];
    const float* eps_rp1    = (const float*)d_in[7];
    const float* conv1_w    = (const float*)d_in[8];
    const float* conv1_b    = (const float*)d_in[9];
    const float* conv2_w    = (const float*)d_in[10];
    const float* conv2_b    = (const float*)d_in[11];
    const float* mlp_w1     = (const float*)d_in[12];
    const float* mlp_b1     = (const float*)d_in[13];
    const float* mlp_w2     = (const float*)d_in[14];
    const float* mlp_b2     = (const float*)d_in[15];
    const float* mlp_w3     = (const float*)d_in[16];
    const float* mlp_b3     = (const float*)d_in[17];
    const float* W_ih       = (const float*)d_in[18];
    const float* b_ih       = (const float*)d_in[19];
    const float* W_hh       = (const float*)d_in[20];
    const float* b_hh       = (const float*)d_in[21];
    const float* addr_emb   = (const float*)d_in[22];
    const float* pid_emb    = (const float*)d_in[23];
    const float* sid_emb    = (const float*)d_in[24];
    const float* pid_ext_w  = (const float*)d_in[25];
    const float* pid_ext_b  = (const float*)d_in[26];
    const float* sid_ext_w  = (const float*)d_in[27];
    const float* sid_ext_b  = (const float*)d_in[28];
    const float* rp_ext_w   = (const float*)d_in[29];
    const float* rp_ext_b   = (const float*)d_in[30];
    float* out = (float*)d_out;

    // workspace layout (floats)
    float* ws = (float*)d_ws;
    size_t off = 0;
    float* W_ih_T   = ws + off; off += 432 * 1024;
    float* W_hh_T   = ws + off; off += 256 * 1024;
    float* bias_all = ws + off; off += 7 * 1024;
    float* pid_rows = ws + off; off += 3 * 1024;
    float* sid_rows = ws + off; off += 2 * 1024;
    float* obs_emb  = ws + off; off += (size_t)BATCH * 400;
    float* obs_part = ws + off; off += (size_t)BATCH * 1024;
    float* h0 = ws + off; off += (size_t)BATCH * 256;
    float* c0 = ws + off; off += (size_t)BATCH * 256;
    float* h1 = ws + off; off += (size_t)BATCH * 256;
    float* c1 = ws + off; off += (size_t)BATCH * 256;
    float* rp0      = ws + off; off += (size_t)BATCH * 2;
    float* rp0_emb  = ws + off; off += (size_t)BATCH * 16;
    float* w2t = ws + off; off += 10000;
    float* w3t = ws + off; off += 1600;
    float* w1p = ws + off; off += 384;
    float* w2p = ws + off; off += 6144;
    float* WsampT = W_ih_T + (size_t)400 * 1024;  // rows 400..415 of W_ih_T

    prep_kernel<<<180, 256, 0, stream>>>(W_ih, W_hh, b_ih, b_hh, addr_emb,
                                         pid_emb, sid_emb, mlp_w2, mlp_w3,
                                         conv1_w, conv1_b, conv2_w,
                                         W_ih_T, W_hh_T, bias_all, pid_rows,
                                         sid_rows, w2t, w3t, w1p, w2p);
    conv_kernel<<<BATCH, 256, 0, stream>>>(obs, w1p, w2p, conv2_b, obs_emb);
    obs_gemm<<<BATCH / 16, 512, 0, stream>>>(obs_emb, W_ih_T, obs_part);

    // step0 (aid 0): h=c=0, head pid_logits (3) -> cols 0..2
    lstm_step<0, 1, 3, false, false><<<BATCH / 16, 512, 0, stream>>>(
        nullptr, nullptr, h0, c0, obs_part, bias_all + 0 * 1024,
        nullptr, nullptr, nullptr, nullptr, nullptr,
        pid_ext_w, pid_ext_b, nullptr, out, 0, nullptr);
    // step1 (aid 1): samp=pid_rows[program_id], h0->h1; head sid -> cols 3..4
    lstm_step<1, 1, 2, true, false><<<BATCH / 16, 512, 0, stream>>>(
        h0, c0, h1, c1, obs_part, bias_all + 1 * 1024,
        pid_rows, program_id, nullptr, nullptr, W_hh_T,
        sid_ext_w, sid_ext_b, nullptr, out, 3, nullptr);
    // step2 (aid 4): samp=sid_rows[shape_id], h1->h1 in-place; head rp_b0 -> cols 5..6
    lstm_step<1, 2, 0, true, false><<<BATCH / 16, 512, 0, stream>>>(
        h1, c1, h1, c1, obs_part, bias_all + 2 * 1024,
        sid_rows, shape_id, nullptr, nullptr, W_hh_T,
        rp_ext_w, rp_ext_b, eps_rp, out, 5, nullptr);
    // step1b (aid 2): samp=pid_rows[program_id], h0->h0 in-place; head sid0 -> cols 7..8
    lstm_step<1, 1, 2, true, false><<<BATCH / 16, 512, 0, stream>>>(
        h0, c0, h0, c0, obs_part, bias_all + 3 * 1024,
        pid_rows, program_id, nullptr, nullptr, W_hh_T,
        sid_ext_w, sid_ext_b, nullptr, out, 7, nullptr);
    // step2b (aid 3): samp=sid_rows[shape_id_0]; head sid1 -> cols 9..10
    lstm_step<1, 1, 2, true, false><<<BATCH / 16, 512, 0, stream>>>(
        h0, c0, h0, c0, obs_part, bias_all + 4 * 1024,
        sid_rows, shape_id_0, nullptr, nullptr, W_hh_T,
        sid_ext_w, sid_ext_b, nullptr, out, 9, nullptr);
    // step3b (aid 5): samp=sid_rows[shape_id_1]; head rp0 -> cols 11..12 (+store)
    lstm_step<1, 2, 0, true, true><<<BATCH / 16, 512, 0, stream>>>(
        h0, c0, h0, c0, obs_part, bias_all + 5 * 1024,
        sid_rows, shape_id_1, nullptr, nullptr, W_hh_T,
        rp_ext_w, rp_ext_b, eps_rp0, out, 11, rp0);
    mlp_kernel<<<BATCH, 128, 0, stream>>>(rp0, mlp_w1, mlp_b1, w2t, mlp_b2,
                                          w3t, mlp_b3, rp0_emb);
    // step4b (aid 6): samp = rp0_emb @ W_samp.T; head rp1 -> cols 13..14
    lstm_step<2, 2, 0, true, false><<<BATCH / 16, 512, 0, stream>>>(
        h0, c0, h1, c1, obs_part, bias_all + 6 * 1024,
        nullptr, nullptr, rp0_emb, WsampT, W_hh_T,
        rp_ext_w, rp_ext_b, eps_rp1, out, 13, nullptr);
}

// Round 6
// 699.939 us; speedup vs baseline: 2.0140x; 1.2987x over previous
//
#include <hip/hip_runtime.h>
#include <hip/hip_bf16.h>
#include <math.h>

#define BATCH 4096
#define HID 256
#define OUT_W 15

typedef unsigned short ushort_t;
typedef unsigned int uint_t;

using bf16x8 = __attribute__((ext_vector_type(8))) short;
using f32x4v = __attribute__((ext_vector_type(4))) float;

__device__ __forceinline__ float sigf(float x) { return 1.0f / (1.0f + __expf(-x)); }
__device__ __forceinline__ float tanh_fast(float x) { return 1.0f - 2.0f / (__expf(2.0f * x) + 1.0f); }
__device__ __forceinline__ float bf2f(ushort_t u) { return __uint_as_float(((uint_t)u) << 16); }
__device__ __forceinline__ ushort_t f2bf(float x) {
    uint_t b = __float_as_uint(x);
    return (ushort_t)((b + 0x7fffu + ((b >> 16) & 1u)) >> 16);
}

// ---------------------------------------------------------------------------
// Prep: W_ih transpose (fp32, for obs_gemm + WsampT), per-step biases, samp
// tables, mlp transposes, packed conv weights, W_hh -> bf16 (layout [n][k]).
// ---------------------------------------------------------------------------
__global__ __launch_bounds__(256) void prep_kernel(
    const float* __restrict__ W_ih, const float* __restrict__ W_hh,
    const float* __restrict__ b_ih, const float* __restrict__ b_hh,
    const float* __restrict__ addr_emb, const float* __restrict__ pid_emb,
    const float* __restrict__ sid_emb,
    const float* __restrict__ mlp_w2, const float* __restrict__ mlp_w3,
    const float* __restrict__ conv1_w, const float* __restrict__ conv1_b,
    const float* __restrict__ conv2_w,
    float* __restrict__ W_ih_T, ushort_t* __restrict__ Wb,
    float* __restrict__ bias_all, float* __restrict__ pid_rows,
    float* __restrict__ sid_rows, float* __restrict__ w2t, float* __restrict__ w3t,
    float* __restrict__ w1p, float* __restrict__ w2p)
{
    int blk = blockIdx.x, t = threadIdx.x;
    if (blk < 112) {
        // W_ih (1024x432) -> W_ih_T (432x1024)
        __shared__ float tile[64][65];
        int j0 = (blk & 15) * 64;
        int k0 = (blk >> 4) * 64;
        for (int i = t; i < 4096; i += 256) {
            int r = i >> 6, c = i & 63;
            int k = k0 + c;
            tile[r][c] = (k < 432) ? W_ih[(size_t)(j0 + r) * 432 + k] : 0.f;
        }
        __syncthreads();
        for (int i = t; i < 4096; i += 256) {
            int r = i >> 6, c = i & 63;
            int k = k0 + r;
            if (k < 432) W_ih_T[(size_t)k * 1024 + j0 + c] = tile[c][r];
        }
    } else if (blk == 112) {
        const int aids[7] = {0, 1, 4, 2, 3, 5, 6};
        for (int s = 0; s < 7; s++) {
            int aid = aids[s];
            for (int j = t; j < 1024; j += 256) {
                float v = b_ih[j] + b_hh[j];
                #pragma unroll
                for (int k = 0; k < 16; k++)
                    v += addr_emb[aid * 16 + k] * W_ih[(size_t)j * 432 + 416 + k];
                bias_all[s * 1024 + j] = v;
            }
        }
    } else if (blk == 113) {
        for (int p = 0; p < 3; p++)
            for (int j = t; j < 1024; j += 256) {
                float v = 0.f;
                #pragma unroll
                for (int k = 0; k < 16; k++)
                    v += pid_emb[p * 16 + k] * W_ih[(size_t)j * 432 + 400 + k];
                pid_rows[p * 1024 + j] = v;
            }
        for (int p = 0; p < 2; p++)
            for (int j = t; j < 1024; j += 256) {
                float v = 0.f;
                #pragma unroll
                for (int k = 0; k < 16; k++)
                    v += sid_emb[p * 16 + k] * W_ih[(size_t)j * 432 + 400 + k];
                sid_rows[p * 1024 + j] = v;
            }
    } else if (blk == 114) {
        for (int i = t; i < 10000; i += 256) {
            int o = i / 100, k = i % 100;
            w2t[k * 100 + o] = mlp_w2[i];
        }
        for (int i = t; i < 1600; i += 256) {
            int o = i / 100, k = i % 100;
            w3t[k * 16 + o] = mlp_w3[i];
        }
    } else if (blk == 115) {
        for (int i = t; i < 384; i += 256) {
            int ic = i / 12, k = i % 12;
            float v = 0.f;
            if (k < 9) v = conv1_w[ic * 9 + k];
            else if (k == 9) v = conv1_b[ic];
            w1p[i] = v;
        }
        for (int i = t; i < 6144; i += 256) {
            int ic = i / 192, rem = i % 192, oc = rem / 12, k = rem % 12;
            w2p[i] = (k < 9) ? conv2_w[(size_t)(oc * 32 + ic) * 9 + k] : 0.f;
        }
    } else {
        // W_hh (1024x256) fp32 -> bf16, same [n][k] layout
        int seg = blk - 116;  // 0..7
        for (int i = seg * 32768 + t; i < (seg + 1) * 32768; i += 256)
            Wb[i] = f2bf(W_hh[i]);
    }
}

// ---------------------------------------------------------------------------
// Conv encoder (fused, LDS-broadcast weights).
// ---------------------------------------------------------------------------
__global__ __launch_bounds__(256, 3) void conv_kernel(
    const float* __restrict__ obs, const float* __restrict__ w1p,
    const float* __restrict__ w2p, const float* __restrict__ b2,
    float* __restrict__ obs_emb)
{
    __shared__ float sm[68 * 68];      // 18496 B
    __shared__ float w2s[32 * 192];    // 24576 B  [ic][oc][12]
    __shared__ float w1s[32 * 12];     // 1536 B   [ic][12]
    const int b = blockIdx.x, t = threadIdx.x;
    const float* og = obs + (size_t)b * 4096;

    #pragma unroll
    for (int i = 0; i < 5; i++) {
        int idx = t + i * 256;
        if (idx < 68 * 68 / 4) ((float4*)sm)[idx] = float4{0.f, 0.f, 0.f, 0.f};
    }
    #pragma unroll
    for (int i = 0; i < 6; i++)
        ((float4*)w2s)[t + i * 256] = ((const float4*)w2p)[t + i * 256];
    if (t < 96) ((float4*)w1s)[t] = ((const float4*)w1p)[t];
    __syncthreads();
    #pragma unroll
    for (int i = 0; i < 4; i++) {
        int idx4 = t + i * 256;
        int row = idx4 >> 4, c4 = idx4 & 15;
        float4 v = ((const float4*)og)[idx4];
        *((float4*)&sm[(row + 4) * 68 + 4 * c4 + 4]) = v;
    }
    __syncthreads();

    const int y = t >> 4, x = t & 15;
    float P[7][8];
    #pragma unroll
    for (int r = 0; r < 7; r++) {
        const float4* p = (const float4*)&sm[(4 * y + 1 + r) * 68 + 4 * x];
        float4 a = p[0], c = p[1];
        P[r][0] = a.x; P[r][1] = a.y; P[r][2] = a.z; P[r][3] = a.w;
        P[r][4] = c.x; P[r][5] = c.y; P[r][6] = c.z; P[r][7] = c.w;
    }

    float acc[16];
    #pragma unroll
    for (int o = 0; o < 16; o++) acc[o] = b2[o];
    const float mr0 = (y == 0) ? 0.f : 1.f;
    const float mc0 = (x == 0) ? 0.f : 1.f;

    #pragma unroll 1
    for (int ic = 0; ic < 32; ic++) {
        const float* q = &w1s[ic * 12];
        float4 qa = *(const float4*)q;
        float4 qb = *(const float4*)(q + 4);
        float w8 = q[8], bb = q[9];
        float wv[9] = {qa.x, qa.y, qa.z, qa.w, qb.x, qb.y, qb.z, qb.w, w8};

        float c1p[9];
        #pragma unroll
        for (int j = 0; j < 3; j++) {
            #pragma unroll
            for (int i = 0; i < 3; i++) {
                float s = bb;
                #pragma unroll
                for (int dy = 0; dy < 3; dy++)
                    #pragma unroll
                    for (int dx = 0; dx < 3; dx++)
                        s += wv[dy * 3 + dx] * P[2 * j + dy][2 * i + dx + 1];
                s = fmaxf(s, 0.f);
                if (j == 0) s *= mr0;
                if (i == 0) s *= mc0;
                c1p[j * 3 + i] = s;
            }
        }
        #pragma unroll
        for (int o = 0; o < 16; o++) {
            const float* wp = &w2s[ic * 192 + o * 12];
            float4 wa = *(const float4*)wp;
            float4 wb = *(const float4*)(wp + 4);
            float w8b = wp[8];
            acc[o] += c1p[0] * wa.x + c1p[1] * wa.y + c1p[2] * wa.z +
                      c1p[3] * wa.w + c1p[4] * wb.x + c1p[5] * wb.y +
                      c1p[6] * wb.z + c1p[7] * wb.w + c1p[8] * w8b;
        }
    }

    __syncthreads();
    float* c2f = sm;
    #pragma unroll
    for (int o = 0; o < 16; o++)
        c2f[(o * 16 + y) * 16 + x] = fmaxf(acc[o], 0.f);
    __syncthreads();
    for (int p = t; p < 400; p += 256) {
        int c = p / 25, rem = p % 25, py = rem / 5, px = rem % 5;
        float s = 0.f;
        #pragma unroll
        for (int dy = 0; dy < 3; dy++)
            #pragma unroll
            for (int dx = 0; dx < 3; dx++)
                s += c2f[(c * 16 + 3 * py + dy) * 16 + 3 * px + dx];
        obs_emb[(size_t)b * 400 + p] = s * (1.f / 9.f);
    }
}

// ---------------------------------------------------------------------------
// obs_part (bf16) = obs_emb (B x 400) @ W_obs.T -> (B x 1024)
// ---------------------------------------------------------------------------
__global__ __launch_bounds__(512) void obs_gemm(
    const float* __restrict__ A, const float* __restrict__ Wt,
    ushort_t* __restrict__ outp)
{
    __shared__ float as_t[400][20];
    __shared__ float Ws[8 * 1024];
    const int t = threadIdx.x;
    const int u = t & 255;
    const int mh = t >> 8;
    const int b0 = blockIdx.x * 16;
    float acc[8][4];
    #pragma unroll
    for (int m = 0; m < 8; m++)
        #pragma unroll
        for (int g = 0; g < 4; g++) acc[m][g] = 0.f;

    for (int i = t; i < 16 * 400; i += 512) {
        int r = i / 400, c = i % 400;
        as_t[c][r] = A[(size_t)(b0 + r) * 400 + c];
    }
    for (int kt = 0; kt < 50; kt++) {
        __syncthreads();
        int k0 = kt * 8;
        #pragma unroll
        for (int i = 0; i < 4; i++) {
            int f = t + i * 512;
            int rr = f >> 8, cc = f & 255;
            ((float4*)Ws)[f] = ((const float4*)(Wt + (size_t)(k0 + rr) * 1024))[cc];
        }
        __syncthreads();
        #pragma unroll
        for (int kk = 0; kk < 8; kk++) {
            float w0 = Ws[kk * 1024 + u];
            float w1 = Ws[kk * 1024 + u + 256];
            float w2 = Ws[kk * 1024 + u + 512];
            float w3 = Ws[kk * 1024 + u + 768];
            const float4* hp = (const float4*)&as_t[k0 + kk][mh * 8];
            float4 ha = hp[0], hb = hp[1];
            float hv[8] = {ha.x, ha.y, ha.z, ha.w, hb.x, hb.y, hb.z, hb.w};
            #pragma unroll
            for (int m = 0; m < 8; m++) {
                acc[m][0] += hv[m] * w0;
                acc[m][1] += hv[m] * w1;
                acc[m][2] += hv[m] * w2;
                acc[m][3] += hv[m] * w3;
            }
        }
    }
    #pragma unroll
    for (int m = 0; m < 8; m++) {
        size_t row = b0 + mh * 8 + m;
        #pragma unroll
        for (int g = 0; g < 4; g++)
            outp[row * 1024 + u + 256 * g] = f2bf(acc[m][g]);
    }
}

// ---------------------------------------------------------------------------
// step0 elementwise: h=c=0 -> c0 (fp32), hb0 (bf16). pre = obs_part + bias0.
// ---------------------------------------------------------------------------
__global__ __launch_bounds__(256) void step0_ew(
    const ushort_t* __restrict__ obs_part, const float* __restrict__ bias_s,
    float* __restrict__ c_out, ushort_t* __restrict__ hb_out)
{
    const int R = blockIdx.x, u = threadIdx.x;
    float pre[4];
    #pragma unroll
    for (int g = 0; g < 4; g++)
        pre[g] = bf2f(obs_part[(size_t)R * 1024 + g * 256 + u]) + bias_s[g * 256 + u];
    float c2 = sigf(pre[0]) * tanh_fast(pre[2]);
    float hv = sigf(pre[3]) * tanh_fast(c2);
    c_out[(size_t)R * 256 + u] = c2;
    hb_out[(size_t)R * 256 + u] = f2bf(hv);
}

// ---------------------------------------------------------------------------
// MFMA LSTM step. Grid 512 blocks (64 m-tiles x 8 unit-groups), 512 threads.
// Wave w: m-sub = 16*(w&3), unit-sub = 16*(w>>2); computes ALL 4 gates for
// its (16 rows x 16 units) -> LSTM nonlinearity in-register from C frags.
// A (h) staged in LDS bf16, row stride 264 ushorts (+16B pad); B = W_hh bf16
// [n][k] fragments straight from global (L2-resident).
// ---------------------------------------------------------------------------
template <int SAMP, int HEAD_N>
__global__ __launch_bounds__(512, 4) void lstm_mfma(
    const ushort_t* __restrict__ hb_in, const float* __restrict__ c_in,
    ushort_t* __restrict__ hb_out, float* __restrict__ c_out,
    const ushort_t* __restrict__ obs_part, const float* __restrict__ bias_s,
    const float* __restrict__ samp_rows, const int* __restrict__ samp_idx,
    const float* __restrict__ rp0_emb, const float* __restrict__ WsampT,
    const ushort_t* __restrict__ Wb,
    const float* __restrict__ head_w, const float* __restrict__ head_b,
    float* __restrict__ out, int out_off)
{
    __shared__ ushort_t hAs[64 * 264];   // 33792 B, row stride 528 B
    __shared__ float hws[3 * 256];       // head weights
    __shared__ float red[64 * 8 * 3];    // head partials
    const int t = threadIdx.x;
    const int bm = blockIdx.x & 63, bu = blockIdx.x >> 6;
    const int b0 = bm * 64;

    // stage 64 rows x 256 bf16 = 2048 float4 (FIX: was 1024 -> half the rows)
    #pragma unroll
    for (int i = 0; i < 4; i++) {
        int idx = t + i * 512, row = idx >> 5, c = idx & 31;
        float4 v = reinterpret_cast<const float4*>(hb_in + (size_t)(b0 + row) * 256)[c];
        *reinterpret_cast<float4*>(&hAs[row * 264 + c * 8]) = v;
    }
    if (HEAD_N > 0 && bu == 0)
        for (int i = t; i < HEAD_N * 256; i += 512) hws[i] = head_w[i];
    __syncthreads();

    const int w = t >> 6, L = t & 63, q = L >> 4, ln = L & 15;
    const int m0 = (w & 3) * 16;
    const int U = bu * 32 + (w >> 2) * 16;
    const int unit = U + ln;

    bf16x8 a[8];
    #pragma unroll
    for (int kk = 0; kk < 8; kk++)
        a[kk] = *reinterpret_cast<const bf16x8*>(&hAs[(m0 + ln) * 264 + kk * 32 + q * 8]);

    f32x4v acc[4];
    #pragma unroll
    for (int g = 0; g < 4; g++) {
        f32x4v z = {0.f, 0.f, 0.f, 0.f};
        const ushort_t* wrow = Wb + (size_t)(g * 256 + unit) * 256 + q * 8;
        #pragma unroll
        for (int kk = 0; kk < 8; kk++) {
            bf16x8 bv = *reinterpret_cast<const bf16x8*>(wrow + kk * 32);
            z = __builtin_amdgcn_mfma_f32_16x16x32_bf16(a[kk], bv, z, 0, 0, 0);
        }
        acc[g] = z;
    }

    #pragma unroll
    for (int r = 0; r < 4; r++) {
        const int R = b0 + m0 + q * 4 + r;
        float pre[4];
        #pragma unroll
        for (int g = 0; g < 4; g++) {
            int col = g * 256 + unit;
            pre[g] = acc[g][r] + bf2f(obs_part[(size_t)R * 1024 + col]) + bias_s[col];
        }
        if (SAMP == 1) {
            int si = samp_idx[R];
            #pragma unroll
            for (int g = 0; g < 4; g++) pre[g] += samp_rows[si * 1024 + g * 256 + unit];
        }
        if (SAMP == 2) {
            #pragma unroll
            for (int k = 0; k < 16; k++) {
                float e = rp0_emb[(size_t)R * 16 + k];
                #pragma unroll
                for (int g = 0; g < 4; g++) pre[g] += e * WsampT[k * 1024 + g * 256 + unit];
            }
        }
        float ci = c_in[(size_t)R * 256 + unit];
        float c2 = sigf(pre[1]) * ci + sigf(pre[0]) * tanh_fast(pre[2]);
        float hv = sigf(pre[3]) * tanh_fast(c2);
        c_out[(size_t)R * 256 + unit] = c2;
        hb_out[(size_t)R * 256 + unit] = f2bf(hv);
    }

    if (HEAD_N > 0 && bu == 0) {
        // head on h_in (rows b0..b0+63) from hAs
        const int row = t >> 3, seg = t & 7;
        float part[3] = {0.f, 0.f, 0.f};
        #pragma unroll
        for (int j = 0; j < 4; j++) {
            uint4 v = *reinterpret_cast<const uint4*>(&hAs[row * 264 + seg * 32 + j * 8]);
            uint_t dw[4] = {v.x, v.y, v.z, v.w};
            #pragma unroll
            for (int d = 0; d < 4; d++) {
                float f0 = __uint_as_float(dw[d] << 16);
                float f1 = __uint_as_float(dw[d] & 0xffff0000u);
                int k = seg * 32 + j * 8 + d * 2;
                #pragma unroll
                for (int n = 0; n < HEAD_N; n++)
                    part[n] += f0 * hws[n * 256 + k] + f1 * hws[n * 256 + k + 1];
            }
        }
        #pragma unroll
        for (int n = 0; n < HEAD_N; n++) red[(row * 8 + seg) * 3 + n] = part[n];
        __syncthreads();
        if (t < 64) {
            #pragma unroll
            for (int n = 0; n < HEAD_N; n++) {
                float s = head_b[n];
                #pragma unroll
                for (int p = 0; p < 8; p++) s += red[(t * 8 + p) * 3 + n];
                out[(size_t)(b0 + t) * OUT_W + out_off + n] = s;
            }
        }
    }
}

// ---------------------------------------------------------------------------
// rp head: out[:, off:off+2] = rp[:, :2] + exp(rp[:, 2:]) * eps, from hb.
// ---------------------------------------------------------------------------
__global__ __launch_bounds__(256) void rp_head(
    const ushort_t* __restrict__ hb, const float* __restrict__ head_w,
    const float* __restrict__ head_b, const float* __restrict__ eps,
    float* __restrict__ out, int out_off, float* __restrict__ rp_store)
{
    __shared__ float hw[1024];
    __shared__ float red[64 * 4 * 4];
    const int t = threadIdx.x;
    const int b0 = blockIdx.x * 64;
    for (int i = t; i < 1024; i += 256) hw[i] = head_w[i];
    __syncthreads();
    const int r = t >> 2, p = t & 3;
    {
        const int R = b0 + r;
        float part[4] = {0.f, 0.f, 0.f, 0.f};
        const ushort_t* hr = hb + (size_t)R * 256 + p * 64;
        #pragma unroll
        for (int j = 0; j < 8; j++) {
            uint4 v = *reinterpret_cast<const uint4*>(hr + j * 8);
            uint_t dw[4] = {v.x, v.y, v.z, v.w};
            #pragma unroll
            for (int d = 0; d < 4; d++) {
                float f0 = __uint_as_float(dw[d] << 16);
                float f1 = __uint_as_float(dw[d] & 0xffff0000u);
                int k = p * 64 + j * 8 + d * 2;
                #pragma unroll
                for (int n = 0; n < 4; n++)
                    part[n] += f0 * hw[n * 256 + k] + f1 * hw[n * 256 + k + 1];
            }
        }
        #pragma unroll
        for (int n = 0; n < 4; n++) red[(r * 4 + p) * 4 + n] = part[n];
    }
    __syncthreads();
    if (t < 64) {
        const int R = b0 + t;
        float s[4];
        #pragma unroll
        for (int n = 0; n < 4; n++) {
            float v = head_b[n];
            #pragma unroll
            for (int p2 = 0; p2 < 4; p2++) v += red[(t * 4 + p2) * 4 + n];
            s[n] = v;
        }
        float v0 = s[0] + __expf(s[2]) * eps[(size_t)R * 2 + 0];
        float v1 = s[1] + __expf(s[3]) * eps[(size_t)R * 2 + 1];
        out[(size_t)R * OUT_W + out_off + 0] = v0;
        out[(size_t)R * OUT_W + out_off + 1] = v1;
        if (rp_store) {
            rp_store[(size_t)R * 2 + 0] = v0;
            rp_store[(size_t)R * 2 + 1] = v1;
        }
    }
}

// ---------------------------------------------------------------------------
// MLP: rp0 (B x 2) -> 100 -> 100 -> rp0_emb (B x 16)
// ---------------------------------------------------------------------------
__global__ __launch_bounds__(128) void mlp_kernel(
    const float* __restrict__ rp0, const float* __restrict__ w1,
    const float* __restrict__ b1, const float* __restrict__ w2t,
    const float* __restrict__ b2, const float* __restrict__ w3t,
    const float* __restrict__ b3, float* __restrict__ emb)
{
    __shared__ float z1[100], z2[100];
    int row = blockIdx.x, t = threadIdx.x;
    float r0 = rp0[(size_t)row * 2], r1 = rp0[(size_t)row * 2 + 1];
    if (t < 100) z1[t] = tanh_fast(b1[t] + w1[t * 2] * r0 + w1[t * 2 + 1] * r1);
    __syncthreads();
    if (t < 100) {
        float s = b2[t];
        for (int k = 0; k < 100; k++) s += w2t[k * 100 + t] * z1[k];
        z2[t] = tanh_fast(s);
    }
    __syncthreads();
    if (t < 16) {
        float s = b3[t];
        for (int k = 0; k < 100; k++) s += w3t[k * 16 + t] * z2[k];
        emb[(size_t)row * 16 + t] = s;
    }
}

// ---------------------------------------------------------------------------
extern "C" void kernel_launch(void* const* d_in, const int* in_sizes, int n_in,
                              void* d_out, int out_size, void* d_ws, size_t ws_size,
                              hipStream_t stream)
{
    const float* obs        = (const float*)d_in[0];
    const int*   program_id = (const int*)d_in[1];
    const int*   shape_id   = (const int*)d_in[2];
    const int*   shape_id_0 = (const int*)d_in[3];
    const int*   shape_id_1 = (const int*)d_in[4];
    const float* eps_rp     = (const float*)d_in[5];
    const float* eps_rp0    = (const float*)d_in[6];
    const float* eps_rp1    = (const float*)d_in[7];
    const float* conv1_w    = (const float*)d_in[8];
    const float* conv1_b    = (const float*)d_in[9];
    const float* conv2_w    = (const float*)d_in[10];
    const float* conv2_b    = (const float*)d_in[11];
    const float* mlp_w1     = (const float*)d_in[12];
    const float* mlp_b1     = (const float*)d_in[13];
    const float* mlp_w2     = (const float*)d_in[14];
    const float* mlp_b2     = (const float*)d_in[15];
    const float* mlp_w3     = (const float*)d_in[16];
    const float* mlp_b3     = (const float*)d_in[17];
    const float* W_ih       = (const float*)d_in[18];
    const float* b_ih       = (const float*)d_in[19];
    const float* W_hh       = (const float*)d_in[20];
    const float* b_hh       = (const float*)d_in[21];
    const float* addr_emb   = (const float*)d_in[22];
    const float* pid_emb    = (const float*)d_in[23];
    const float* sid_emb    = (const float*)d_in[24];
    const float* pid_ext_w  = (const float*)d_in[25];
    const float* pid_ext_b  = (const float*)d_in[26];
    const float* sid_ext_w  = (const float*)d_in[27];
    const float* sid_ext_b  = (const float*)d_in[28];
    const float* rp_ext_w   = (const float*)d_in[29];
    const float* rp_ext_b   = (const float*)d_in[30];
    float* out = (float*)d_out;

    // workspace layout (float slots, 16B-aligned chunks)
    float* ws = (float*)d_ws;
    size_t off = 0;
    float* W_ih_T   = ws + off; off += 432 * 1024;              // fp32
    ushort_t* Wb    = (ushort_t*)(ws + off); off += 131072;     // bf16 1024x256
    float* bias_all = ws + off; off += 7 * 1024;
    float* pid_rows = ws + off; off += 3 * 1024;
    float* sid_rows = ws + off; off += 2 * 1024;
    float* obs_emb  = ws + off; off += (size_t)BATCH * 400;
    ushort_t* obs_part = (ushort_t*)(ws + off); off += (size_t)BATCH * 512;  // bf16 Bx1024
    ushort_t* hb0 = (ushort_t*)(ws + off); off += (size_t)BATCH * 128;      // bf16 Bx256
    ushort_t* hbA = (ushort_t*)(ws + off); off += (size_t)BATCH * 128;
    ushort_t* hbB = (ushort_t*)(ws + off); off += (size_t)BATCH * 128;
    ushort_t* hbC = (ushort_t*)(ws + off); off += (size_t)BATCH * 128;
    float* c0 = ws + off; off += (size_t)BATCH * 256;
    float* cA = ws + off; off += (size_t)BATCH * 256;
    float* cB = ws + off; off += (size_t)BATCH * 256;
    float* cC = ws + off; off += (size_t)BATCH * 256;
    float* cD = ws + off; off += (size_t)BATCH * 256;   // dump for terminal c
    float* rp0      = ws + off; off += (size_t)BATCH * 2;
    float* rp0_emb  = ws + off; off += (size_t)BATCH * 16;
    float* w2t = ws + off; off += 10000;
    float* w3t = ws + off; off += 1600;
    float* w1p = ws + off; off += 384;
    float* w2p = ws + off; off += 6144;
    float* WsampT = W_ih_T + (size_t)400 * 1024;  // rows 400..415 of W_ih_T (fp32)

    prep_kernel<<<124, 256, 0, stream>>>(W_ih, W_hh, b_ih, b_hh, addr_emb,
                                         pid_emb, sid_emb, mlp_w2, mlp_w3,
                                         conv1_w, conv1_b, conv2_w,
                                         W_ih_T, Wb, bias_all, pid_rows,
                                         sid_rows, w2t, w3t, w1p, w2p);
    conv_kernel<<<BATCH, 256, 0, stream>>>(obs, w1p, w2p, conv2_b, obs_emb);
    obs_gemm<<<BATCH / 16, 512, 0, stream>>>(obs_emb, W_ih_T, obs_part);

    // step0 (aid 0): h=c=0 -> hb0, c0 (pid head on h0 folded into step1)
    step0_ew<<<BATCH, 256, 0, stream>>>(obs_part, bias_all + 0 * 1024, c0, hb0);

    // step1 (aid 1): hb0,c0 -> hbA,cA; samp pid; head = pid_logits(3) on h0 -> cols 0..2
    lstm_mfma<1, 3><<<512, 512, 0, stream>>>(
        hb0, c0, hbA, cA, obs_part, bias_all + 1 * 1024,
        pid_rows, program_id, nullptr, nullptr, Wb,
        pid_ext_w, pid_ext_b, out, 0);
    // step2 (aid 4): hbA,cA -> hbB,cD; samp sid[shape_id]; head = sid(2) on h1 -> cols 3..4
    lstm_mfma<1, 2><<<512, 512, 0, stream>>>(
        hbA, cA, hbB, cD, obs_part, bias_all + 2 * 1024,
        sid_rows, shape_id, nullptr, nullptr, Wb,
        sid_ext_w, sid_ext_b, out, 3);
    // rp_b0 head on h2 (hbB) -> cols 5..6
    rp_head<<<64, 256, 0, stream>>>(hbB, rp_ext_w, rp_ext_b, eps_rp, out, 5, nullptr);
    // step1b (aid 2): hb0,c0 -> hbA,cA; samp pid; no head
    lstm_mfma<1, 0><<<512, 512, 0, stream>>>(
        hb0, c0, hbA, cA, obs_part, bias_all + 3 * 1024,
        pid_rows, program_id, nullptr, nullptr, Wb,
        nullptr, nullptr, out, 0);
    // step2b (aid 3): hbA,cA -> hbB,cB; samp sid[shape_id_0]; head = sid0(2) on h1b -> cols 7..8
    lstm_mfma<1, 2><<<512, 512, 0, stream>>>(
        hbA, cA, hbB, cB, obs_part, bias_all + 4 * 1024,
        sid_rows, shape_id_0, nullptr, nullptr, Wb,
        sid_ext_w, sid_ext_b, out, 7);
    // step3b (aid 5): hbB,cB -> hbC,cC; samp sid[shape_id_1]; head = sid1(2) on h2b -> cols 9..10
    lstm_mfma<1, 2><<<512, 512, 0, stream>>>(
        hbB, cB, hbC, cC, obs_part, bias_all + 5 * 1024,
        sid_rows, shape_id_1, nullptr, nullptr, Wb,
        sid_ext_w, sid_ext_b, out, 9);
    // rp0 head on h3b (hbC) -> cols 11..12, store rp0
    rp_head<<<64, 256, 0, stream>>>(hbC, rp_ext_w, rp_ext_b, eps_rp0, out, 11, rp0);
    mlp_kernel<<<BATCH, 128, 0, stream>>>(rp0, mlp_w1, mlp_b1, w2t, mlp_b2,
                                          w3t, mlp_b3, rp0_emb);
    // step4b (aid 6): hbC,cC -> hbB,cD; samp = rp0_emb @ WsampT; no head
    lstm_mfma<2, 0><<<512, 512, 0, stream>>>(
        hbC, cC, hbB, cD, obs_part, bias_all + 6 * 1024,
        nullptr, nullptr, rp0_emb, WsampT, Wb,
        nullptr, nullptr, out, 0);
    // rp1 head on h4b (hbB) -> cols 13..14
    rp_head<<<64, 256, 0, stream>>>(hbB, rp_ext_w, rp_ext_b, eps_rp1, out, 13, nullptr);
}

// Round 7
// 545.528 us; speedup vs baseline: 2.5841x; 1.2830x over previous
//
#include <hip/hip_runtime.h>
#include <hip/hip_bf16.h>
#include <math.h>

#define BATCH 4096
#define HID 256
#define OUT_W 15

typedef unsigned short ushort_t;
typedef unsigned int uint_t;

using bf16x8 = __attribute__((ext_vector_type(8))) short;
using f32x4v = __attribute__((ext_vector_type(4))) float;

__device__ __forceinline__ float sigf(float x) { return 1.0f / (1.0f + __expf(-x)); }
__device__ __forceinline__ float tanh_fast(float x) { return 1.0f - 2.0f / (__expf(2.0f * x) + 1.0f); }
__device__ __forceinline__ float bf2f(ushort_t u) { return __uint_as_float(((uint_t)u) << 16); }
__device__ __forceinline__ ushort_t f2bf(float x) {
    uint_t b = __float_as_uint(x);
    return (ushort_t)((b + 0x7fffu + ((b >> 16) & 1u)) >> 16);
}

// ---------------------------------------------------------------------------
// Prep: W_ih transpose, per-step biases, samp tables, mlp transposes,
// packed conv1 weights w1p[ic][12], conv2 B-fragments Btg[tap][oc][ic] bf16,
// W_hh -> bf16 [n][k].
// ---------------------------------------------------------------------------
__global__ __launch_bounds__(256) void prep_kernel(
    const float* __restrict__ W_ih, const float* __restrict__ W_hh,
    const float* __restrict__ b_ih, const float* __restrict__ b_hh,
    const float* __restrict__ addr_emb, const float* __restrict__ pid_emb,
    const float* __restrict__ sid_emb,
    const float* __restrict__ mlp_w2, const float* __restrict__ mlp_w3,
    const float* __restrict__ conv1_w, const float* __restrict__ conv1_b,
    const float* __restrict__ conv2_w,
    float* __restrict__ W_ih_T, ushort_t* __restrict__ Wb,
    float* __restrict__ bias_all, float* __restrict__ pid_rows,
    float* __restrict__ sid_rows, float* __restrict__ w2t, float* __restrict__ w3t,
    float* __restrict__ w1p, ushort_t* __restrict__ Btg)
{
    int blk = blockIdx.x, t = threadIdx.x;
    if (blk < 112) {
        // W_ih (1024x432) -> W_ih_T (432x1024)
        __shared__ float tile[64][65];
        int j0 = (blk & 15) * 64;
        int k0 = (blk >> 4) * 64;
        for (int i = t; i < 4096; i += 256) {
            int r = i >> 6, c = i & 63;
            int k = k0 + c;
            tile[r][c] = (k < 432) ? W_ih[(size_t)(j0 + r) * 432 + k] : 0.f;
        }
        __syncthreads();
        for (int i = t; i < 4096; i += 256) {
            int r = i >> 6, c = i & 63;
            int k = k0 + r;
            if (k < 432) W_ih_T[(size_t)k * 1024 + j0 + c] = tile[c][r];
        }
    } else if (blk == 112) {
        const int aids[7] = {0, 1, 4, 2, 3, 5, 6};
        for (int s = 0; s < 7; s++) {
            int aid = aids[s];
            for (int j = t; j < 1024; j += 256) {
                float v = b_ih[j] + b_hh[j];
                #pragma unroll
                for (int k = 0; k < 16; k++)
                    v += addr_emb[aid * 16 + k] * W_ih[(size_t)j * 432 + 416 + k];
                bias_all[s * 1024 + j] = v;
            }
        }
    } else if (blk == 113) {
        for (int p = 0; p < 3; p++)
            for (int j = t; j < 1024; j += 256) {
                float v = 0.f;
                #pragma unroll
                for (int k = 0; k < 16; k++)
                    v += pid_emb[p * 16 + k] * W_ih[(size_t)j * 432 + 400 + k];
                pid_rows[p * 1024 + j] = v;
            }
        for (int p = 0; p < 2; p++)
            for (int j = t; j < 1024; j += 256) {
                float v = 0.f;
                #pragma unroll
                for (int k = 0; k < 16; k++)
                    v += sid_emb[p * 16 + k] * W_ih[(size_t)j * 432 + 400 + k];
                sid_rows[p * 1024 + j] = v;
            }
    } else if (blk == 114) {
        for (int i = t; i < 10000; i += 256) {
            int o = i / 100, k = i % 100;
            w2t[k * 100 + o] = mlp_w2[i];
        }
        for (int i = t; i < 1600; i += 256) {
            int o = i / 100, k = i % 100;
            w3t[k * 16 + o] = mlp_w3[i];
        }
    } else if (blk == 115) {
        for (int i = t; i < 384; i += 256) {
            int ic = i / 12, k = i % 12;
            float v = 0.f;
            if (k < 9) v = conv1_w[ic * 9 + k];
            else if (k == 9) v = conv1_b[ic];
            w1p[i] = v;
        }
        // Btg[(tap*16 + oc)*32 + ic] = conv2_w[(oc*32+ic)*9 + tap]
        for (int i = t; i < 4608; i += 256) {
            int tap = i >> 9;
            int rem = i & 511;
            int oc = rem >> 5, ic = rem & 31;
            Btg[i] = f2bf(conv2_w[(size_t)(oc * 32 + ic) * 9 + tap]);
        }
    } else {
        // W_hh (1024x256) fp32 -> bf16, same [n][k] layout
        int seg = blk - 116;  // 0..7
        for (int i = seg * 32768 + t; i < (seg + 1) * 32768; i += 256)
            Wb[i] = f2bf(W_hh[i]);
    }
}

// ---------------------------------------------------------------------------
// Conv encoder v2: cooperative c1 in LDS (bf16, even/odd column phase-split)
// + conv2 as 9 tap-shifted MFMA GEMMs (16x16x32 bf16, K=32=ic).
// One block (256 thr) per image; LDS ~115 KB -> 1 block/CU.
//   c1 buf rows: c1 row -1..31 -> buf row 0..32 (row 0 = zero pad)
//   even cols 0..30 -> cE idx 0..15;  odd cols -1..31 -> cO idx 0..16
//   position stride 40 ushorts (80 B): conflict-free A-frag ds_read_b128.
// ---------------------------------------------------------------------------
#define CE_RS 680   // cE row stride in ushorts (17 pos * 40)
#define CO_RS 760   // cO row stride in ushorts (19 pos * 40)
__global__ __launch_bounds__(256, 1) void conv_kernel(
    const float* __restrict__ obs, const float* __restrict__ w1p,
    const ushort_t* __restrict__ Btg, const float* __restrict__ b2,
    float* __restrict__ obs_emb)
{
    __shared__ __align__(16) float sm[68 * 68];        // 18496 B
    __shared__ __align__(16) ushort_t cE[33 * CE_RS];  // 44880 B
    __shared__ __align__(16) ushort_t cO[33 * CO_RS];  // 50160 B
    __shared__ __align__(16) float w1s[384];           // 1536 B
    const int b = blockIdx.x, t = threadIdx.x;
    const float* og = obs + (size_t)b * 4096;

    // zero obs halo buffer + borders of c1 bufs; load w1s
    #pragma unroll
    for (int i = 0; i < 5; i++) {
        int idx = t + i * 256;
        if (idx < 68 * 68 / 4) ((float4*)sm)[idx] = float4{0.f, 0.f, 0.f, 0.f};
    }
    {
        uint_t* zE = (uint_t*)cE;
        uint_t* zO = (uint_t*)cO;
        for (int i = t; i < 340; i += 256) zE[i] = 0;            // cE row 0
        for (int i = t; i < 380; i += 256) zO[i] = 0;            // cO row 0
        for (int i = t; i < 640; i += 256) {                     // cO col 0, rows 1..32
            int row = i / 20 + 1, d = i % 20;
            zO[row * (CO_RS / 2) + d] = 0;
        }
    }
    if (t < 96) ((float4*)w1s)[t] = ((const float4*)w1p)[t];
    __syncthreads();
    #pragma unroll
    for (int i = 0; i < 4; i++) {
        int idx4 = t + i * 256;
        int row = idx4 >> 4, c4 = idx4 & 15;
        float4 v = ((const float4*)og)[idx4];
        *((float4*)&sm[(row + 4) * 68 + 4 * c4 + 4]) = v;
    }
    __syncthreads();

    // ---- conv1: thread (r = t>>3, g = t&7) computes c1 row r, cols 4g..4g+3,
    //      all 32 ic. obs patch rows 2r-1..2r+1, cols 8g-4..8g+7 in regs.
    {
        const int r = t >> 3, g = t & 7;
        float Pt[3][12];
        #pragma unroll
        for (int d = 0; d < 3; d++) {
            const float* src = &sm[(2 * r + 3 + d) * 68 + 8 * g];
            #pragma unroll
            for (int j4 = 0; j4 < 3; j4++) {
                float4 v = ((const float4*)src)[j4];
                Pt[d][j4 * 4 + 0] = v.x; Pt[d][j4 * 4 + 1] = v.y;
                Pt[d][j4 * 4 + 2] = v.z; Pt[d][j4 * 4 + 3] = v.w;
            }
        }
        // Pt[d][j] = obs[2r-1+d][8g-4+j]; obs col needed = 8g+2p-1+dx -> j = 2p+3+dx
        for (int round = 0; round < 4; round++) {
            uint_t pk[4][4];
            #pragma unroll
            for (int icl = 0; icl < 8; icl++) {
                int ic = round * 8 + icl;
                const float* qw = &w1s[ic * 12];
                float4 qa = *(const float4*)qw;
                float4 qb = *(const float4*)(qw + 4);
                float w8 = qw[8], bb = qw[9];
                float wv[9] = {qa.x, qa.y, qa.z, qa.w, qb.x, qb.y, qb.z, qb.w, w8};
                #pragma unroll
                for (int p = 0; p < 3 + 1; p++) {
                    float s = bb;
                    #pragma unroll
                    for (int d = 0; d < 3; d++)
                        #pragma unroll
                        for (int dx = 0; dx < 3; dx++)
                            s += wv[d * 3 + dx] * Pt[d][2 * p + 3 + dx];
                    s = fmaxf(s, 0.f);
                    ushort_t u = f2bf(s);
                    if (icl & 1) pk[p][icl >> 1] |= ((uint_t)u) << 16;
                    else         pk[p][icl >> 1] = u;
                }
            }
            #pragma unroll
            for (int p = 0; p < 4; p++) {
                int c = 4 * g + p;
                ushort_t* dst;
                if ((c & 1) == 0) dst = &cE[(r + 1) * CE_RS + (c >> 1) * 40 + round * 8];
                else              dst = &cO[(r + 1) * CO_RS + ((c + 1) >> 1) * 40 + round * 8];
                *(uint4*)dst = uint4{pk[p][0], pk[p][1], pk[p][2], pk[p][3]};
            }
        }
    }
    __syncthreads();

    // ---- conv2: 9 tap-GEMMs via MFMA. Wave w: output rows y = 4w..4w+3.
    // A[m=ln] = c1[2y-1+dy][2ln-1+dx][ic0..31]; B = Btg[tap][oc=ln][k=ic].
    const int w = t >> 6, L = t & 63, q = L >> 4, ln = L & 15;
    bf16x8 Bv[9];
    #pragma unroll
    for (int tap = 0; tap < 9; tap++)
        Bv[tap] = *reinterpret_cast<const bf16x8*>(&Btg[(tap * 16 + ln) * 32 + q * 8]);

    f32x4v Cacc[4];
    #pragma unroll
    for (int i = 0; i < 4; i++) Cacc[i] = f32x4v{0.f, 0.f, 0.f, 0.f};

    #pragma unroll
    for (int i = 0; i < 4; i++) {
        int y = w * 4 + i;
        #pragma unroll
        for (int dy = 0; dy < 3; dy++) {
            int row = 2 * y + dy;  // buf row = c1 row (2y-1+dy) + 1
            bf16x8 a0 = *reinterpret_cast<const bf16x8*>(&cO[row * CO_RS + ln * 40 + q * 8]);        // dx=0: col 2ln-1
            bf16x8 a1 = *reinterpret_cast<const bf16x8*>(&cE[row * CE_RS + ln * 40 + q * 8]);        // dx=1: col 2ln
            bf16x8 a2 = *reinterpret_cast<const bf16x8*>(&cO[row * CO_RS + (ln + 1) * 40 + q * 8]);  // dx=2: col 2ln+1
            Cacc[i] = __builtin_amdgcn_mfma_f32_16x16x32_bf16(a0, Bv[dy * 3 + 0], Cacc[i], 0, 0, 0);
            Cacc[i] = __builtin_amdgcn_mfma_f32_16x16x32_bf16(a1, Bv[dy * 3 + 1], Cacc[i], 0, 0, 0);
            Cacc[i] = __builtin_amdgcn_mfma_f32_16x16x32_bf16(a2, Bv[dy * 3 + 2], Cacc[i], 0, 0, 0);
        }
    }
    __syncthreads();  // all MFMA A-reads done before overlaying c2 on cE

    // ---- epilogue: bias+relu -> c2 buffer (fp32, oc stride 260 dw), pool
    float* c2b = (float*)cE;  // 16*260*4 = 16640 B
    {
        float bb2 = b2[ln];
        #pragma unroll
        for (int i = 0; i < 4; i++) {
            int y = w * 4 + i;  // C row m = q*4+r -> x
            float4 o;
            o.x = fmaxf(Cacc[i][0] + bb2, 0.f);
            o.y = fmaxf(Cacc[i][1] + bb2, 0.f);
            o.z = fmaxf(Cacc[i][2] + bb2, 0.f);
            o.w = fmaxf(Cacc[i][3] + bb2, 0.f);
            *(float4*)&c2b[ln * 260 + y * 16 + q * 4] = o;
        }
    }
    __syncthreads();
    for (int p = t; p < 400; p += 256) {
        int c = p / 25, rem = p % 25, py = rem / 5, px = rem % 5;
        float s = 0.f;
        #pragma unroll
        for (int dy = 0; dy < 3; dy++)
            #pragma unroll
            for (int dx = 0; dx < 3; dx++)
                s += c2b[c * 260 + (3 * py + dy) * 16 + 3 * px + dx];
        obs_emb[(size_t)b * 400 + p] = s * (1.f / 9.f);
    }
}

// ---------------------------------------------------------------------------
// obs_part (bf16) = obs_emb (B x 400) @ W_obs.T -> (B x 1024)
// ---------------------------------------------------------------------------
__global__ __launch_bounds__(512) void obs_gemm(
    const float* __restrict__ A, const float* __restrict__ Wt,
    ushort_t* __restrict__ outp)
{
    __shared__ float as_t[400][20];
    __shared__ float Ws[8 * 1024];
    const int t = threadIdx.x;
    const int u = t & 255;
    const int mh = t >> 8;
    const int b0 = blockIdx.x * 16;
    float acc[8][4];
    #pragma unroll
    for (int m = 0; m < 8; m++)
        #pragma unroll
        for (int g = 0; g < 4; g++) acc[m][g] = 0.f;

    for (int i = t; i < 16 * 400; i += 512) {
        int r = i / 400, c = i % 400;
        as_t[c][r] = A[(size_t)(b0 + r) * 400 + c];
    }
    for (int kt = 0; kt < 50; kt++) {
        __syncthreads();
        int k0 = kt * 8;
        #pragma unroll
        for (int i = 0; i < 4; i++) {
            int f = t + i * 512;
            int rr = f >> 8, cc = f & 255;
            ((float4*)Ws)[f] = ((const float4*)(Wt + (size_t)(k0 + rr) * 1024))[cc];
        }
        __syncthreads();
        #pragma unroll
        for (int kk = 0; kk < 8; kk++) {
            float w0 = Ws[kk * 1024 + u];
            float w1 = Ws[kk * 1024 + u + 256];
            float w2 = Ws[kk * 1024 + u + 512];
            float w3 = Ws[kk * 1024 + u + 768];
            const float4* hp = (const float4*)&as_t[k0 + kk][mh * 8];
            float4 ha = hp[0], hb = hp[1];
            float hv[8] = {ha.x, ha.y, ha.z, ha.w, hb.x, hb.y, hb.z, hb.w};
            #pragma unroll
            for (int m = 0; m < 8; m++) {
                acc[m][0] += hv[m] * w0;
                acc[m][1] += hv[m] * w1;
                acc[m][2] += hv[m] * w2;
                acc[m][3] += hv[m] * w3;
            }
        }
    }
    #pragma unroll
    for (int m = 0; m < 8; m++) {
        size_t row = b0 + mh * 8 + m;
        #pragma unroll
        for (int g = 0; g < 4; g++)
            outp[row * 1024 + u + 256 * g] = f2bf(acc[m][g]);
    }
}

// ---------------------------------------------------------------------------
// step0 elementwise: h=c=0 -> c0 (fp32), hb0 (bf16). pre = obs_part + bias0.
// ---------------------------------------------------------------------------
__global__ __launch_bounds__(256) void step0_ew(
    const ushort_t* __restrict__ obs_part, const float* __restrict__ bias_s,
    float* __restrict__ c_out, ushort_t* __restrict__ hb_out)
{
    const int R = blockIdx.x, u = threadIdx.x;
    float pre[4];
    #pragma unroll
    for (int g = 0; g < 4; g++)
        pre[g] = bf2f(obs_part[(size_t)R * 1024 + g * 256 + u]) + bias_s[g * 256 + u];
    float c2 = sigf(pre[0]) * tanh_fast(pre[2]);
    float hv = sigf(pre[3]) * tanh_fast(c2);
    c_out[(size_t)R * 256 + u] = c2;
    hb_out[(size_t)R * 256 + u] = f2bf(hv);
}

// ---------------------------------------------------------------------------
// MFMA LSTM step (as R6, passing).
// ---------------------------------------------------------------------------
template <int SAMP, int HEAD_N>
__global__ __launch_bounds__(512, 4) void lstm_mfma(
    const ushort_t* __restrict__ hb_in, const float* __restrict__ c_in,
    ushort_t* __restrict__ hb_out, float* __restrict__ c_out,
    const ushort_t* __restrict__ obs_part, const float* __restrict__ bias_s,
    const float* __restrict__ samp_rows, const int* __restrict__ samp_idx,
    const float* __restrict__ rp0_emb, const float* __restrict__ WsampT,
    const ushort_t* __restrict__ Wb,
    const float* __restrict__ head_w, const float* __restrict__ head_b,
    float* __restrict__ out, int out_off)
{
    __shared__ ushort_t hAs[64 * 264];   // 33792 B, row stride 528 B
    __shared__ float hws[3 * 256];       // head weights
    __shared__ float red[64 * 8 * 3];    // head partials
    const int t = threadIdx.x;
    const int bm = blockIdx.x & 63, bu = blockIdx.x >> 6;
    const int b0 = bm * 64;

    #pragma unroll
    for (int i = 0; i < 4; i++) {
        int idx = t + i * 512, row = idx >> 5, c = idx & 31;
        float4 v = reinterpret_cast<const float4*>(hb_in + (size_t)(b0 + row) * 256)[c];
        *reinterpret_cast<float4*>(&hAs[row * 264 + c * 8]) = v;
    }
    if (HEAD_N > 0 && bu == 0)
        for (int i = t; i < HEAD_N * 256; i += 512) hws[i] = head_w[i];
    __syncthreads();

    const int w = t >> 6, L = t & 63, q = L >> 4, ln = L & 15;
    const int m0 = (w & 3) * 16;
    const int U = bu * 32 + (w >> 2) * 16;
    const int unit = U + ln;

    bf16x8 a[8];
    #pragma unroll
    for (int kk = 0; kk < 8; kk++)
        a[kk] = *reinterpret_cast<const bf16x8*>(&hAs[(m0 + ln) * 264 + kk * 32 + q * 8]);

    f32x4v acc[4];
    #pragma unroll
    for (int g = 0; g < 4; g++) {
        f32x4v z = {0.f, 0.f, 0.f, 0.f};
        const ushort_t* wrow = Wb + (size_t)(g * 256 + unit) * 256 + q * 8;
        #pragma unroll
        for (int kk = 0; kk < 8; kk++) {
            bf16x8 bv = *reinterpret_cast<const bf16x8*>(wrow + kk * 32);
            z = __builtin_amdgcn_mfma_f32_16x16x32_bf16(a[kk], bv, z, 0, 0, 0);
        }
        acc[g] = z;
    }

    #pragma unroll
    for (int r = 0; r < 4; r++) {
        const int R = b0 + m0 + q * 4 + r;
        float pre[4];
        #pragma unroll
        for (int g = 0; g < 4; g++) {
            int col = g * 256 + unit;
            pre[g] = acc[g][r] + bf2f(obs_part[(size_t)R * 1024 + col]) + bias_s[col];
        }
        if (SAMP == 1) {
            int si = samp_idx[R];
            #pragma unroll
            for (int g = 0; g < 4; g++) pre[g] += samp_rows[si * 1024 + g * 256 + unit];
        }
        if (SAMP == 2) {
            #pragma unroll
            for (int k = 0; k < 16; k++) {
                float e = rp0_emb[(size_t)R * 16 + k];
                #pragma unroll
                for (int g = 0; g < 4; g++) pre[g] += e * WsampT[k * 1024 + g * 256 + unit];
            }
        }
        float ci = c_in[(size_t)R * 256 + unit];
        float c2 = sigf(pre[1]) * ci + sigf(pre[0]) * tanh_fast(pre[2]);
        float hv = sigf(pre[3]) * tanh_fast(c2);
        c_out[(size_t)R * 256 + unit] = c2;
        hb_out[(size_t)R * 256 + unit] = f2bf(hv);
    }

    if (HEAD_N > 0 && bu == 0) {
        const int row = t >> 3, seg = t & 7;
        float part[3] = {0.f, 0.f, 0.f};
        #pragma unroll
        for (int j = 0; j < 4; j++) {
            uint4 v = *reinterpret_cast<const uint4*>(&hAs[row * 264 + seg * 32 + j * 8]);
            uint_t dw[4] = {v.x, v.y, v.z, v.w};
            #pragma unroll
            for (int d = 0; d < 4; d++) {
                float f0 = __uint_as_float(dw[d] << 16);
                float f1 = __uint_as_float(dw[d] & 0xffff0000u);
                int k = seg * 32 + j * 8 + d * 2;
                #pragma unroll
                for (int n = 0; n < HEAD_N; n++)
                    part[n] += f0 * hws[n * 256 + k] + f1 * hws[n * 256 + k + 1];
            }
        }
        #pragma unroll
        for (int n = 0; n < HEAD_N; n++) red[(row * 8 + seg) * 3 + n] = part[n];
        __syncthreads();
        if (t < 64) {
            #pragma unroll
            for (int n = 0; n < HEAD_N; n++) {
                float s = head_b[n];
                #pragma unroll
                for (int p = 0; p < 8; p++) s += red[(t * 8 + p) * 3 + n];
                out[(size_t)(b0 + t) * OUT_W + out_off + n] = s;
            }
        }
    }
}

// ---------------------------------------------------------------------------
// rp head: out[:, off:off+2] = rp[:, :2] + exp(rp[:, 2:]) * eps, from hb.
// ---------------------------------------------------------------------------
__global__ __launch_bounds__(256) void rp_head(
    const ushort_t* __restrict__ hb, const float* __restrict__ head_w,
    const float* __restrict__ head_b, const float* __restrict__ eps,
    float* __restrict__ out, int out_off, float* __restrict__ rp_store)
{
    __shared__ float hw[1024];
    __shared__ float red[64 * 4 * 4];
    const int t = threadIdx.x;
    const int b0 = blockIdx.x * 64;
    for (int i = t; i < 1024; i += 256) hw[i] = head_w[i];
    __syncthreads();
    const int r = t >> 2, p = t & 3;
    {
        const int R = b0 + r;
        float part[4] = {0.f, 0.f, 0.f, 0.f};
        const ushort_t* hr = hb + (size_t)R * 256 + p * 64;
        #pragma unroll
        for (int j = 0; j < 8; j++) {
            uint4 v = *reinterpret_cast<const uint4*>(hr + j * 8);
            uint_t dw[4] = {v.x, v.y, v.z, v.w};
            #pragma unroll
            for (int d = 0; d < 4; d++) {
                float f0 = __uint_as_float(dw[d] << 16);
                float f1 = __uint_as_float(dw[d] & 0xffff0000u);
                int k = p * 64 + j * 8 + d * 2;
                #pragma unroll
                for (int n = 0; n < 4; n++)
                    part[n] += f0 * hw[n * 256 + k] + f1 * hw[n * 256 + k + 1];
            }
        }
        #pragma unroll
        for (int n = 0; n < 4; n++) red[(r * 4 + p) * 4 + n] = part[n];
    }
    __syncthreads();
    if (t < 64) {
        const int R = b0 + t;
        float s[4];
        #pragma unroll
        for (int n = 0; n < 4; n++) {
            float v = head_b[n];
            #pragma unroll
            for (int p2 = 0; p2 < 4; p2++) v += red[(t * 4 + p2) * 4 + n];
            s[n] = v;
        }
        float v0 = s[0] + __expf(s[2]) * eps[(size_t)R * 2 + 0];
        float v1 = s[1] + __expf(s[3]) * eps[(size_t)R * 2 + 1];
        out[(size_t)R * OUT_W + out_off + 0] = v0;
        out[(size_t)R * OUT_W + out_off + 1] = v1;
        if (rp_store) {
            rp_store[(size_t)R * 2 + 0] = v0;
            rp_store[(size_t)R * 2 + 1] = v1;
        }
    }
}

// ---------------------------------------------------------------------------
// MLP: rp0 (B x 2) -> 100 -> 100 -> rp0_emb (B x 16)
// ---------------------------------------------------------------------------
__global__ __launch_bounds__(128) void mlp_kernel(
    const float* __restrict__ rp0, const float* __restrict__ w1,
    const float* __restrict__ b1, const float* __restrict__ w2t,
    const float* __restrict__ b2, const float* __restrict__ w3t,
    const float* __restrict__ b3, float* __restrict__ emb)
{
    __shared__ float z1[100], z2[100];
    int row = blockIdx.x, t = threadIdx.x;
    float r0 = rp0[(size_t)row * 2], r1 = rp0[(size_t)row * 2 + 1];
    if (t < 100) z1[t] = tanh_fast(b1[t] + w1[t * 2] * r0 + w1[t * 2 + 1] * r1);
    __syncthreads();
    if (t < 100) {
        float s = b2[t];
        for (int k = 0; k < 100; k++) s += w2t[k * 100 + t] * z1[k];
        z2[t] = tanh_fast(s);
    }
    __syncthreads();
    if (t < 16) {
        float s = b3[t];
        for (int k = 0; k < 100; k++) s += w3t[k * 16 + t] * z2[k];
        emb[(size_t)row * 16 + t] = s;
    }
}

// ---------------------------------------------------------------------------
extern "C" void kernel_launch(void* const* d_in, const int* in_sizes, int n_in,
                              void* d_out, int out_size, void* d_ws, size_t ws_size,
                              hipStream_t stream)
{
    const float* obs        = (const float*)d_in[0];
    const int*   program_id = (const int*)d_in[1];
    const int*   shape_id   = (const int*)d_in[2];
    const int*   shape_id_0 = (const int*)d_in[3];
    const int*   shape_id_1 = (const int*)d_in[4];
    const float* eps_rp     = (const float*)d_in[5];
    const float* eps_rp0    = (const float*)d_in[6];
    const float* eps_rp1    = (const float*)d_in[7];
    const float* conv1_w    = (const float*)d_in[8];
    const float* conv1_b    = (const float*)d_in[9];
    const float* conv2_w    = (const float*)d_in[10];
    const float* conv2_b    = (const float*)d_in[11];
    const float* mlp_w1     = (const float*)d_in[12];
    const float* mlp_b1     = (const float*)d_in[13];
    const float* mlp_w2     = (const float*)d_in[14];
    const float* mlp_b2     = (const float*)d_in[15];
    const float* mlp_w3     = (const float*)d_in[16];
    const float* mlp_b3     = (const float*)d_in[17];
    const float* W_ih       = (const float*)d_in[18];
    const float* b_ih       = (const float*)d_in[19];
    const float* W_hh       = (const float*)d_in[20];
    const float* b_hh       = (const float*)d_in[21];
    const float* addr_emb   = (const float*)d_in[22];
    const float* pid_emb    = (const float*)d_in[23];
    const float* sid_emb    = (const float*)d_in[24];
    const float* pid_ext_w  = (const float*)d_in[25];
    const float* pid_ext_b  = (const float*)d_in[26];
    const float* sid_ext_w  = (const float*)d_in[27];
    const float* sid_ext_b  = (const float*)d_in[28];
    const float* rp_ext_w   = (const float*)d_in[29];
    const float* rp_ext_b   = (const float*)d_in[30];
    float* out = (float*)d_out;

    // workspace layout (float slots, 16B-aligned chunks)
    float* ws = (float*)d_ws;
    size_t off = 0;
    float* W_ih_T   = ws + off; off += 432 * 1024;              // fp32
    ushort_t* Wb    = (ushort_t*)(ws + off); off += 131072;     // bf16 1024x256
    float* bias_all = ws + off; off += 7 * 1024;
    float* pid_rows = ws + off; off += 3 * 1024;
    float* sid_rows = ws + off; off += 2 * 1024;
    float* obs_emb  = ws + off; off += (size_t)BATCH * 400;
    ushort_t* obs_part = (ushort_t*)(ws + off); off += (size_t)BATCH * 512;  // bf16 Bx1024
    ushort_t* hb0 = (ushort_t*)(ws + off); off += (size_t)BATCH * 128;      // bf16 Bx256
    ushort_t* hbA = (ushort_t*)(ws + off); off += (size_t)BATCH * 128;
    ushort_t* hbB = (ushort_t*)(ws + off); off += (size_t)BATCH * 128;
    ushort_t* hbC = (ushort_t*)(ws + off); off += (size_t)BATCH * 128;
    float* c0 = ws + off; off += (size_t)BATCH * 256;
    float* cA = ws + off; off += (size_t)BATCH * 256;
    float* cB = ws + off; off += (size_t)BATCH * 256;
    float* cC = ws + off; off += (size_t)BATCH * 256;
    float* cD = ws + off; off += (size_t)BATCH * 256;   // dump for terminal c
    float* rp0      = ws + off; off += (size_t)BATCH * 2;
    float* rp0_emb  = ws + off; off += (size_t)BATCH * 16;
    float* w2t = ws + off; off += 10000;
    float* w3t = ws + off; off += 1600;
    float* w1p = ws + off; off += 384;
    ushort_t* Btg = (ushort_t*)(ws + off); off += 2304;  // 4608 bf16
    float* WsampT = W_ih_T + (size_t)400 * 1024;  // rows 400..415 of W_ih_T (fp32)

    prep_kernel<<<124, 256, 0, stream>>>(W_ih, W_hh, b_ih, b_hh, addr_emb,
                                         pid_emb, sid_emb, mlp_w2, mlp_w3,
                                         conv1_w, conv1_b, conv2_w,
                                         W_ih_T, Wb, bias_all, pid_rows,
                                         sid_rows, w2t, w3t, w1p, Btg);
    conv_kernel<<<BATCH, 256, 0, stream>>>(obs, w1p, Btg, conv2_b, obs_emb);
    obs_gemm<<<BATCH / 16, 512, 0, stream>>>(obs_emb, W_ih_T, obs_part);

    // step0 (aid 0): h=c=0 -> hb0, c0 (pid head on h0 folded into step1)
    step0_ew<<<BATCH, 256, 0, stream>>>(obs_part, bias_all + 0 * 1024, c0, hb0);

    // step1 (aid 1): hb0,c0 -> hbA,cA; samp pid; head = pid_logits(3) on h0 -> cols 0..2
    lstm_mfma<1, 3><<<512, 512, 0, stream>>>(
        hb0, c0, hbA, cA, obs_part, bias_all + 1 * 1024,
        pid_rows, program_id, nullptr, nullptr, Wb,
        pid_ext_w, pid_ext_b, out, 0);
    // step2 (aid 4): hbA,cA -> hbB,cD; samp sid[shape_id]; head = sid(2) on h1 -> cols 3..4
    lstm_mfma<1, 2><<<512, 512, 0, stream>>>(
        hbA, cA, hbB, cD, obs_part, bias_all + 2 * 1024,
        sid_rows, shape_id, nullptr, nullptr, Wb,
        sid_ext_w, sid_ext_b, out, 3);
    // rp_b0 head on h2 (hbB) -> cols 5..6
    rp_head<<<64, 256, 0, stream>>>(hbB, rp_ext_w, rp_ext_b, eps_rp, out, 5, nullptr);
    // step1b (aid 2): hb0,c0 -> hbA,cA; samp pid; no head
    lstm_mfma<1, 0><<<512, 512, 0, stream>>>(
        hb0, c0, hbA, cA, obs_part, bias_all + 3 * 1024,
        pid_rows, program_id, nullptr, nullptr, Wb,
        nullptr, nullptr, out, 0);
    // step2b (aid 3): hbA,cA -> hbB,cB; samp sid[shape_id_0]; head = sid0(2) on h1b -> cols 7..8
    lstm_mfma<1, 2><<<512, 512, 0, stream>>>(
        hbA, cA, hbB, cB, obs_part, bias_all + 4 * 1024,
        sid_rows, shape_id_0, nullptr, nullptr, Wb,
        sid_ext_w, sid_ext_b, out, 7);
    // step3b (aid 5): hbB,cB -> hbC,cC; samp sid[shape_id_1]; head = sid1(2) on h2b -> cols 9..10
    lstm_mfma<1, 2><<<512, 512, 0, stream>>>(
        hbB, cB, hbC, cC, obs_part, bias_all + 5 * 1024,
        sid_rows, shape_id_1, nullptr, nullptr, Wb,
        sid_ext_w, sid_ext_b, out, 9);
    // rp0 head on h3b (hbC) -> cols 11..12, store rp0
    rp_head<<<64, 256, 0, stream>>>(hbC, rp_ext_w, rp_ext_b, eps_rp0, out, 11, rp0);
    mlp_kernel<<<BATCH, 128, 0, stream>>>(rp0, mlp_w1, mlp_b1, w2t, mlp_b2,
                                          w3t, mlp_b3, rp0_emb);
    // step4b (aid 6): hbC,cC -> hbB,cD; samp = rp0_emb @ WsampT; no head
    lstm_mfma<2, 0><<<512, 512, 0, stream>>>(
        hbC, cC, hbB, cD, obs_part, bias_all + 6 * 1024,
        nullptr, nullptr, rp0_emb, WsampT, Wb,
        nullptr, nullptr, out, 0);
    // rp1 head on h4b (hbB) -> cols 13..14
    rp_head<<<64, 256, 0, stream>>>(hbB, rp_ext_w, rp_ext_b, eps_rp1, out, 13, nullptr);
}